// Round 3
// baseline (720.666 us; speedup 1.0000x reference)
//
#include <hip/hip_runtime.h>

#define NBUK 8

// ---------------- bucket histogram (8 dst-range buckets) ----------------
__global__ void k_bcount(const int* __restrict__ dst, int* __restrict__ bcnt,
                         int E, int binsz) {
    __shared__ int s[NBUK];
    if (threadIdx.x < NBUK) s[threadIdx.x] = 0;
    __syncthreads();
    int stride = gridDim.x * blockDim.x;
    int E4 = E >> 2;
    const int4* d4 = (const int4*)dst;
    for (int i = blockIdx.x * blockDim.x + threadIdx.x; i < E4; i += stride) {
        int4 v = d4[i];
        atomicAdd(&s[(unsigned)v.x / (unsigned)binsz], 1);
        atomicAdd(&s[(unsigned)v.y / (unsigned)binsz], 1);
        atomicAdd(&s[(unsigned)v.z / (unsigned)binsz], 1);
        atomicAdd(&s[(unsigned)v.w / (unsigned)binsz], 1);
    }
    // tail
    if (blockIdx.x == 0 && threadIdx.x < (E & 3))
        atomicAdd(&s[(unsigned)dst[E4 * 4 + threadIdx.x] / (unsigned)binsz], 1);
    __syncthreads();
    if (threadIdx.x < NBUK) atomicAdd(&bcnt[threadIdx.x], s[threadIdx.x]);
}

__global__ void k_bscan(const int* __restrict__ bcnt, int* __restrict__ bbase,
                        int* __restrict__ bcur, int E) {
    if (threadIdx.x == 0 && blockIdx.x == 0) {
        int acc = 0;
        for (int b = 0; b < NBUK; b++) { bbase[b] = acc; bcur[b] = acc; acc += bcnt[b]; }
        bbase[NBUK] = acc;
    }
}

// ---------------- partition edges into dst-range buckets ----------------
__global__ void k_part(const int* __restrict__ src, const int* __restrict__ dst,
                       int* __restrict__ bcur, int2* __restrict__ ebuf,
                       int E, int binsz) {
    __shared__ int scnt[NBUK];
    __shared__ int sbase[NBUK];
    int base = blockIdx.x * 2048;
    if (threadIdx.x < NBUK) scnt[threadIdx.x] = 0;
    __syncthreads();
    int ed[8], es[8], eb[8], ep[8];
    #pragma unroll
    for (int j = 0; j < 8; j++) {
        int i = base + j * 256 + threadIdx.x;
        if (i < E) {
            int d = dst[i]; ed[j] = d; es[j] = src[i];
            int b = (unsigned)d / (unsigned)binsz; eb[j] = b;
            ep[j] = atomicAdd(&scnt[b], 1);
        } else eb[j] = -1;
    }
    __syncthreads();
    if (threadIdx.x < NBUK)
        sbase[threadIdx.x] = atomicAdd(&bcur[threadIdx.x], scnt[threadIdx.x]);
    __syncthreads();
    #pragma unroll
    for (int j = 0; j < 8; j++)
        if (eb[j] >= 0)
            ebuf[sbase[eb[j]] + ep[j]] = make_int2(ed[j], es[j]);
}

// ---------------- per-XCD count / fill from bucketed edges ----------------
__global__ void k_cnt_x(const int2* __restrict__ ebuf, const int* __restrict__ bbase,
                        int* __restrict__ deg) {
    int g = blockIdx.x & 7;
    int slot = blockIdx.x >> 3;
    int lo = bbase[g], hi = bbase[g + 1];
    int stride = (gridDim.x >> 3) * blockDim.x;
    for (int i = lo + slot * blockDim.x + threadIdx.x; i < hi; i += stride)
        atomicAdd(&deg[ebuf[i].x], 1);
}

__global__ void k_fill_x(const int2* __restrict__ ebuf, const int* __restrict__ bbase,
                         int* __restrict__ cursor, int* __restrict__ csr) {
    int g = blockIdx.x & 7;
    int slot = blockIdx.x >> 3;
    int lo = bbase[g], hi = bbase[g + 1];
    int stride = (gridDim.x >> 3) * blockDim.x;
    for (int i = lo + slot * blockDim.x + threadIdx.x; i < hi; i += stride) {
        int2 e = ebuf[i];
        int p = atomicAdd(&cursor[e.x], 1);
        csr[p] = e.y;
    }
}

// ---------------- scans (rowptr, cursor, dinv) ----------------
__global__ void k_scan_a(const int* __restrict__ deg, int* __restrict__ bsum, int n) {
    __shared__ int sdata[256];
    int base = blockIdx.x * 2048;
    int tid = threadIdx.x;
    int sum = 0;
    #pragma unroll
    for (int j = 0; j < 8; j++) {
        int idx = base + tid * 8 + j;
        if (idx < n) sum += deg[idx];
    }
    sdata[tid] = sum;
    __syncthreads();
    for (int s = 128; s > 0; s >>= 1) {
        if (tid < s) sdata[tid] += sdata[tid + s];
        __syncthreads();
    }
    if (tid == 0) bsum[blockIdx.x] = sdata[0];
}

__global__ void k_scan_b(int* __restrict__ bsum, int nb, int* __restrict__ rowptr, int n) {
    if (threadIdx.x == 0 && blockIdx.x == 0) {
        int acc = 0;
        for (int i = 0; i < nb; i++) { int v = bsum[i]; bsum[i] = acc; acc += v; }
        rowptr[n] = acc;
    }
}

__global__ void k_scan_c(const int* __restrict__ deg, const int* __restrict__ boff,
                         int* __restrict__ rowptr, int* __restrict__ cursor,
                         float* __restrict__ dinv, int n) {
    __shared__ int tmp[256];
    int base = blockIdx.x * 2048;
    int tid = threadIdx.x;
    int local[8];
    int tsum = 0;
    #pragma unroll
    for (int j = 0; j < 8; j++) {
        int idx = base + tid * 8 + j;
        int v = (idx < n) ? deg[idx] : 0;
        local[j] = tsum;
        tsum += v;
    }
    tmp[tid] = tsum;
    __syncthreads();
    for (int off = 1; off < 256; off <<= 1) {
        int v = (tid >= off) ? tmp[tid - off] : 0;
        __syncthreads();
        tmp[tid] += v;
        __syncthreads();
    }
    int excl = tmp[tid] - tsum;
    int baseOff = boff[blockIdx.x] + excl;
    #pragma unroll
    for (int j = 0; j < 8; j++) {
        int idx = base + tid * 8 + j;
        if (idx < n) {
            int rp = baseOff + local[j];
            rowptr[idx] = rp;
            cursor[idx] = rp;
            dinv[idx] = rsqrtf((float)deg[idx] + 1.0f);
        }
    }
}

// ---------------- GEMM (vector-ALU f32; W staged in LDS) ----------------
template<int K, int H, bool SCALE, bool BIAS>
__global__ void k_gemm(const float* __restrict__ X, const float* __restrict__ W,
                       const float* __restrict__ bias, const float* __restrict__ dinv,
                       float* __restrict__ Y, int n) {
    __shared__ float Wl[K * H];
    for (int i = threadIdx.x; i < K * H; i += 256) Wl[i] = W[i];
    __syncthreads();
    const int RPB = 16;
    const int RIF = 256 / H;
    int col = threadIdx.x % H;
    int rof = threadIdx.x / H;
    int rowBase = blockIdx.x * RPB;
    for (int r = rof; r < RPB; r += RIF) {
        int row = rowBase + r;
        if (row >= n) continue;
        const float* xr = X + (size_t)row * K;
        float acc = 0.f;
        #pragma unroll
        for (int k = 0; k < K; k += 4) {
            float4 xv = *reinterpret_cast<const float4*>(xr + k);
            acc = fmaf(xv.x, Wl[(k + 0) * H + col], acc);
            acc = fmaf(xv.y, Wl[(k + 1) * H + col], acc);
            acc = fmaf(xv.z, Wl[(k + 2) * H + col], acc);
            acc = fmaf(xv.w, Wl[(k + 3) * H + col], acc);
        }
        if (SCALE) acc *= dinv[row];
        if (BIAS)  acc += bias[col];
        Y[(size_t)row * H + col] = acc;
    }
}

// ---------------- Aggregation: one wave per node, lane = feature ----------
__global__ void k_agg(const int* __restrict__ rowptr, const int* __restrict__ csr,
                      const float* __restrict__ y, const float* __restrict__ dinv,
                      const float* __restrict__ bias, float* __restrict__ out, int n) {
    int wave = (int)((blockIdx.x * (size_t)blockDim.x + threadIdx.x) >> 6);
    int lane = threadIdx.x & 63;
    if (wave >= n) return;
    int node = wave;
    float a0 = y[(size_t)node * 64 + lane];
    float a1 = 0.f, a2 = 0.f, a3 = 0.f;
    int s = rowptr[node];
    int e = rowptr[node + 1];
    for (int base = s; base < e; base += 64) {
        int rem = e - base; int cnt = rem > 64 ? 64 : rem;
        int idx = (base + lane < e) ? csr[base + lane] : 0;
        int j = 0;
        for (; j + 4 <= cnt; j += 4) {
            int s0 = __shfl(idx, j);
            int s1 = __shfl(idx, j + 1);
            int s2 = __shfl(idx, j + 2);
            int s3 = __shfl(idx, j + 3);
            float v0 = y[(size_t)s0 * 64 + lane];
            float v1 = y[(size_t)s1 * 64 + lane];
            float v2 = y[(size_t)s2 * 64 + lane];
            float v3 = y[(size_t)s3 * 64 + lane];
            a0 += v0; a1 += v1; a2 += v2; a3 += v3;
        }
        for (; j < cnt; j++) {
            int s0 = __shfl(idx, j);
            a0 += y[(size_t)s0 * 64 + lane];
        }
    }
    float v = dinv[node] * ((a0 + a1) + (a2 + a3)) + bias[lane];
    out[(size_t)node * 64 + lane] = fmaxf(v, 0.f);
}

// ---------------- launch ----------------
extern "C" void kernel_launch(void* const* d_in, const int* in_sizes, int n_in,
                              void* d_out, int out_size, void* d_ws, size_t ws_size,
                              hipStream_t stream) {
    const float* x  = (const float*)d_in[0];
    const int*   ei = (const int*)d_in[1];
    const float* W1 = (const float*)d_in[2];
    const float* b1 = (const float*)d_in[3];
    const float* W2 = (const float*)d_in[4];
    const float* b2 = (const float*)d_in[5];
    const float* Wl = (const float*)d_in[6];
    const float* bl = (const float*)d_in[7];
    float* out = (float*)d_out;

    const int n = in_sizes[0] / 128;     // 100000
    const int E = in_sizes[1] / 2;       // 3200000
    const int* src = ei;
    const int* dst = ei + E;
    const int binsz = (n + NBUK - 1) / NBUK;

    char* p = (char*)d_ws;
    auto alloc = [&](size_t bytes) { char* r = p; p += (bytes + 255) & ~(size_t)255; return r; };
    float* dinv   = (float*)alloc((size_t)n * 4);
    int*   ctrl   = (int*)  alloc((size_t)(n + 32) * 4);  // deg | bcnt(8) | bcur(8) | bbase(9)
    int*   rowptr = (int*)  alloc((size_t)(n + 1) * 4);
    int*   cursor = (int*)  alloc((size_t)n * 4);
    int*   bsum   = (int*)  alloc(256 * 4);
    int*   csr    = (int*)  alloc((size_t)E * 4);
    float* bufY   = (float*)alloc((size_t)n * 64 * 4);
    float* bufA   = (float*)alloc((size_t)n * 64 * 4);
    float* bufB   = (float*)alloc((size_t)n * 64 * 4);
    (void)ws_size;

    int* deg   = ctrl;
    int* bcnt  = ctrl + n;
    int* bcur  = ctrl + n + 8;
    int* bbase = ctrl + n + 16;
    int2* ebuf = (int2*)bufY;            // alias: ebuf dead before gemm1 writes bufY

    const int NB = (n + 2047) / 2048;    // scan blocks (49)

    hipMemsetAsync(ctrl, 0, (size_t)(n + 16) * 4, stream);
    k_bcount<<<1024, 256, 0, stream>>>(dst, bcnt, E, binsz);
    k_bscan<<<1, 64, 0, stream>>>(bcnt, bbase, bcur, E);
    k_part<<<(E + 2047) / 2048, 256, 0, stream>>>(src, dst, bcur, ebuf, E, binsz);
    k_cnt_x<<<2048, 256, 0, stream>>>(ebuf, bbase, deg);
    k_scan_a<<<NB, 256, 0, stream>>>(deg, bsum, n);
    k_scan_b<<<1, 64, 0, stream>>>(bsum, NB, rowptr, n);
    k_scan_c<<<NB, 256, 0, stream>>>(deg, bsum, rowptr, cursor, dinv, n);
    k_fill_x<<<2048, 256, 0, stream>>>(ebuf, bbase, cursor, csr);

    // layer 1: y = dinv ⊙ (x @ W1); h1 = relu(dinv*agg + b1)
    k_gemm<128, 64, true, false><<<(n + 15) / 16, 256, 0, stream>>>(x, W1, nullptr, dinv, bufY, n);
    k_agg<<<(n + 3) / 4, 256, 0, stream>>>(rowptr, csr, bufY, dinv, b1, bufA, n);

    // layer 2
    k_gemm<64, 64, true, false><<<(n + 15) / 16, 256, 0, stream>>>(bufA, W2, nullptr, dinv, bufB, n);
    k_agg<<<(n + 3) / 4, 256, 0, stream>>>(rowptr, csr, bufB, dinv, b2, bufA, n);

    // head: out = h2 @ Wl + bl
    k_gemm<64, 32, false, true><<<(n + 15) / 16, 256, 0, stream>>>(bufA, Wl, bl, nullptr, out, n);
}

// Round 4
// 512.848 us; speedup vs baseline: 1.4052x; 1.4052x over previous
//
#include <hip/hip_runtime.h>

#define MAXBUK 512          // buckets of 256 dst-nodes; n=100000 -> 391 buckets

// ---------------- fine-bucket histogram of dst ----------------
__global__ void k_bhist(const int* __restrict__ dst, int* __restrict__ bcnt,
                        int E, int nbuk) {
    __shared__ int s[MAXBUK];
    for (int t = threadIdx.x; t < nbuk; t += 256) s[t] = 0;
    __syncthreads();
    int stride = gridDim.x * blockDim.x;
    int E4 = E >> 2;
    const int4* d4 = (const int4*)dst;
    for (int i = blockIdx.x * blockDim.x + threadIdx.x; i < E4; i += stride) {
        int4 v = d4[i];
        atomicAdd(&s[v.x >> 8], 1);
        atomicAdd(&s[v.y >> 8], 1);
        atomicAdd(&s[v.z >> 8], 1);
        atomicAdd(&s[v.w >> 8], 1);
    }
    if (blockIdx.x == 0 && threadIdx.x < (E & 3))
        atomicAdd(&s[dst[(E & ~3) + threadIdx.x] >> 8], 1);
    __syncthreads();
    for (int t = threadIdx.x; t < nbuk; t += 256)
        if (s[t]) atomicAdd(&bcnt[t], s[t]);
}

// serial scan of bucket counts -> bucket bases (= CSR region bases)
__global__ void k_bscan(const int* __restrict__ bcnt, int* __restrict__ bbase,
                        int* __restrict__ bcur, int* __restrict__ rowptr,
                        int nbuk, int n) {
    if (threadIdx.x == 0 && blockIdx.x == 0) {
        int acc = 0;
        for (int b = 0; b < nbuk; b++) { bbase[b] = acc; bcur[b] = acc; acc += bcnt[b]; }
        bbase[nbuk] = acc;
        rowptr[n] = acc;
    }
}

// ---------------- partition edges into bucket-contiguous ebuf ----------------
__global__ void k_part2(const int* __restrict__ src, const int* __restrict__ dst,
                        int* __restrict__ bcur, int2* __restrict__ ebuf,
                        int E, int nbuk) {
    __shared__ int hcnt[MAXBUK];
    __shared__ int gbase[MAXBUK];
    __shared__ int hcur[MAXBUK];
    int base = blockIdx.x * 8192;
    int end = base + 8192; if (end > E) end = E;
    for (int t = threadIdx.x; t < nbuk; t += 256) { hcnt[t] = 0; hcur[t] = 0; }
    __syncthreads();
    for (int i = base + threadIdx.x; i < end; i += 256)
        atomicAdd(&hcnt[dst[i] >> 8], 1);
    __syncthreads();
    for (int t = threadIdx.x; t < nbuk; t += 256)
        gbase[t] = hcnt[t] ? atomicAdd(&bcur[t], hcnt[t]) : 0;
    __syncthreads();
    for (int i = base + threadIdx.x; i < end; i += 256) {
        int d = dst[i];
        int b = d >> 8;
        int p = atomicAdd(&hcur[b], 1);
        ebuf[gbase[b] + p] = make_int2(d, src[i]);
    }
}

// ---------------- per-bucket CSR assembly (one workgroup per bucket) --------
// All csr writes of a bucket land in its own contiguous region -> full-line
// eviction from a single L2; rowptr/dinv derived from the LDS histogram.
__global__ void k_csr(const int2* __restrict__ ebuf, const int* __restrict__ bbase,
                      int* __restrict__ rowptr, float* __restrict__ dinv,
                      int* __restrict__ csr, int n) {
    __shared__ int hist[256];
    __shared__ int scan[256];
    __shared__ int cur[256];
    int b = blockIdx.x;
    int lo = bbase[b], hi = bbase[b + 1];
    int nodebase = b << 8;
    int t = threadIdx.x;
    hist[t] = 0;
    __syncthreads();
    for (int i = lo + t; i < hi; i += 256)
        atomicAdd(&hist[ebuf[i].x & 255], 1);
    __syncthreads();
    int deg = hist[t];
    scan[t] = deg;
    __syncthreads();
    for (int off = 1; off < 256; off <<= 1) {
        int u = (t >= off) ? scan[t - off] : 0;
        __syncthreads();
        scan[t] += u;
        __syncthreads();
    }
    int ex = scan[t] - deg;       // exclusive prefix within bucket
    cur[t] = ex;
    int node = nodebase + t;
    if (node < n) {
        rowptr[node] = lo + ex;
        dinv[node] = rsqrtf((float)deg + 1.0f);
    }
    __syncthreads();
    for (int i = lo + t; i < hi; i += 256) {
        int2 e = ebuf[i];
        int p = atomicAdd(&cur[e.x & 255], 1);
        csr[lo + p] = e.y;
    }
}

// ---------------- GEMM (vector-ALU f32; W staged in LDS) ----------------
template<int K, int H, bool SCALE, bool BIAS>
__global__ void k_gemm(const float* __restrict__ X, const float* __restrict__ W,
                       const float* __restrict__ bias, const float* __restrict__ dinv,
                       float* __restrict__ Y, int n) {
    __shared__ float Wl[K * H];
    for (int i = threadIdx.x; i < K * H; i += 256) Wl[i] = W[i];
    __syncthreads();
    const int RPB = 16;
    const int RIF = 256 / H;
    int col = threadIdx.x % H;
    int rof = threadIdx.x / H;
    int rowBase = blockIdx.x * RPB;
    for (int r = rof; r < RPB; r += RIF) {
        int row = rowBase + r;
        if (row >= n) continue;
        const float* xr = X + (size_t)row * K;
        float acc = 0.f;
        #pragma unroll
        for (int k = 0; k < K; k += 4) {
            float4 xv = *reinterpret_cast<const float4*>(xr + k);
            acc = fmaf(xv.x, Wl[(k + 0) * H + col], acc);
            acc = fmaf(xv.y, Wl[(k + 1) * H + col], acc);
            acc = fmaf(xv.z, Wl[(k + 2) * H + col], acc);
            acc = fmaf(xv.w, Wl[(k + 3) * H + col], acc);
        }
        if (SCALE) acc *= dinv[row];
        if (BIAS)  acc += bias[col];
        Y[(size_t)row * H + col] = acc;
    }
}

// ---------------- Aggregation: one wave per node, lane = feature ----------
__global__ void k_agg(const int* __restrict__ rowptr, const int* __restrict__ csr,
                      const float* __restrict__ y, const float* __restrict__ dinv,
                      const float* __restrict__ bias, float* __restrict__ out, int n) {
    int wave = (int)((blockIdx.x * (size_t)blockDim.x + threadIdx.x) >> 6);
    int lane = threadIdx.x & 63;
    if (wave >= n) return;
    int node = wave;
    float a0 = y[(size_t)node * 64 + lane];
    float a1 = 0.f, a2 = 0.f, a3 = 0.f;
    int s = rowptr[node];
    int e = rowptr[node + 1];
    for (int base = s; base < e; base += 64) {
        int rem = e - base; int cnt = rem > 64 ? 64 : rem;
        int idx = (base + lane < e) ? csr[base + lane] : 0;
        int j = 0;
        for (; j + 4 <= cnt; j += 4) {
            int s0 = __shfl(idx, j);
            int s1 = __shfl(idx, j + 1);
            int s2 = __shfl(idx, j + 2);
            int s3 = __shfl(idx, j + 3);
            float v0 = y[(size_t)s0 * 64 + lane];
            float v1 = y[(size_t)s1 * 64 + lane];
            float v2 = y[(size_t)s2 * 64 + lane];
            float v3 = y[(size_t)s3 * 64 + lane];
            a0 += v0; a1 += v1; a2 += v2; a3 += v3;
        }
        for (; j < cnt; j++) {
            int s0 = __shfl(idx, j);
            a0 += y[(size_t)s0 * 64 + lane];
        }
    }
    float v = dinv[node] * ((a0 + a1) + (a2 + a3)) + bias[lane];
    out[(size_t)node * 64 + lane] = fmaxf(v, 0.f);
}

// ---------------- launch ----------------
extern "C" void kernel_launch(void* const* d_in, const int* in_sizes, int n_in,
                              void* d_out, int out_size, void* d_ws, size_t ws_size,
                              hipStream_t stream) {
    const float* x  = (const float*)d_in[0];
    const int*   ei = (const int*)d_in[1];
    const float* W1 = (const float*)d_in[2];
    const float* b1 = (const float*)d_in[3];
    const float* W2 = (const float*)d_in[4];
    const float* b2 = (const float*)d_in[5];
    const float* Wl = (const float*)d_in[6];
    const float* bl = (const float*)d_in[7];
    float* out = (float*)d_out;

    const int n = in_sizes[0] / 128;     // 100000
    const int E = in_sizes[1] / 2;       // 3200000
    const int* src = ei;
    const int* dst = ei + E;
    const int nbuk = (n + 255) >> 8;     // 391

    char* p = (char*)d_ws;
    auto alloc = [&](size_t bytes) { char* r = p; p += (bytes + 255) & ~(size_t)255; return r; };
    float* dinv   = (float*)alloc((size_t)n * 4);
    int*   bcnt   = (int*)  alloc(MAXBUK * 4);
    int*   bcur   = (int*)  alloc(MAXBUK * 4);
    int*   bbase  = (int*)  alloc((MAXBUK + 1) * 4);
    int*   rowptr = (int*)  alloc((size_t)(n + 1) * 4);
    int*   csr    = (int*)  alloc((size_t)E * 4);
    float* bufY   = (float*)alloc((size_t)n * 64 * 4);
    float* bufA   = (float*)alloc((size_t)n * 64 * 4);
    float* bufB   = (float*)alloc((size_t)n * 64 * 4);
    (void)ws_size;

    int2* ebuf = (int2*)bufY;            // alias: ebuf dead before gemm1 writes bufY

    hipMemsetAsync(bcnt, 0, MAXBUK * 4, stream);
    k_bhist<<<512, 256, 0, stream>>>(dst, bcnt, E, nbuk);
    k_bscan<<<1, 64, 0, stream>>>(bcnt, bbase, bcur, rowptr, nbuk, n);
    k_part2<<<(E + 8191) / 8192, 256, 0, stream>>>(src, dst, bcur, ebuf, E, nbuk);
    k_csr<<<nbuk, 256, 0, stream>>>(ebuf, bbase, rowptr, dinv, csr, n);

    // layer 1: y = dinv ⊙ (x @ W1); h1 = relu(dinv*agg + b1)
    k_gemm<128, 64, true, false><<<(n + 15) / 16, 256, 0, stream>>>(x, W1, nullptr, dinv, bufY, n);
    k_agg<<<(n + 3) / 4, 256, 0, stream>>>(rowptr, csr, bufY, dinv, b1, bufA, n);

    // layer 2
    k_gemm<64, 64, true, false><<<(n + 15) / 16, 256, 0, stream>>>(bufA, W2, nullptr, dinv, bufB, n);
    k_agg<<<(n + 3) / 4, 256, 0, stream>>>(rowptr, csr, bufB, dinv, b2, bufA, n);

    // head: out = h2 @ Wl + bl
    k_gemm<64, 32, false, true><<<(n + 15) / 16, 256, 0, stream>>>(bufA, Wl, bl, nullptr, out, n);
}

// Round 5
// 456.465 us; speedup vs baseline: 1.5788x; 1.1235x over previous
//
#include <hip/hip_runtime.h>

#define MAXBUK 512          // buckets of 256 dst-nodes; n=100000 -> 391 buckets

// ---------------- fine-bucket histogram of dst ----------------
__global__ void k_bhist(const int* __restrict__ dst, int* __restrict__ bcnt,
                        int E, int nbuk) {
    __shared__ int s[MAXBUK];
    for (int t = threadIdx.x; t < nbuk; t += 256) s[t] = 0;
    __syncthreads();
    int stride = gridDim.x * blockDim.x;
    int E4 = E >> 2;
    const int4* d4 = (const int4*)dst;
    for (int i = blockIdx.x * blockDim.x + threadIdx.x; i < E4; i += stride) {
        int4 v = d4[i];
        atomicAdd(&s[v.x >> 8], 1);
        atomicAdd(&s[v.y >> 8], 1);
        atomicAdd(&s[v.z >> 8], 1);
        atomicAdd(&s[v.w >> 8], 1);
    }
    if (blockIdx.x == 0 && threadIdx.x < (E & 3))
        atomicAdd(&s[dst[(E & ~3) + threadIdx.x] >> 8], 1);
    __syncthreads();
    for (int t = threadIdx.x; t < nbuk; t += 256)
        if (s[t]) atomicAdd(&bcnt[t], s[t]);
}

// serial scan of bucket counts -> bucket bases (= CSR region bases)
__global__ void k_bscan(const int* __restrict__ bcnt, int* __restrict__ bbase,
                        int* __restrict__ bcur, int* __restrict__ rowptr,
                        int nbuk, int n) {
    if (threadIdx.x == 0 && blockIdx.x == 0) {
        int acc = 0;
        for (int b = 0; b < nbuk; b++) { bbase[b] = acc; bcur[b] = acc; acc += bcnt[b]; }
        bbase[nbuk] = acc;
        rowptr[n] = acc;
    }
}

// ---------------- partition edges into bucket-contiguous ebuf ----------------
__global__ void k_part2(const int* __restrict__ src, const int* __restrict__ dst,
                        int* __restrict__ bcur, int2* __restrict__ ebuf,
                        int E, int nbuk) {
    __shared__ int hcnt[MAXBUK];
    __shared__ int gbase[MAXBUK];
    __shared__ int hcur[MAXBUK];
    int base = blockIdx.x * 8192;
    int end = base + 8192; if (end > E) end = E;
    for (int t = threadIdx.x; t < nbuk; t += 256) { hcnt[t] = 0; hcur[t] = 0; }
    __syncthreads();
    for (int i = base + threadIdx.x; i < end; i += 256)
        atomicAdd(&hcnt[dst[i] >> 8], 1);
    __syncthreads();
    for (int t = threadIdx.x; t < nbuk; t += 256)
        gbase[t] = hcnt[t] ? atomicAdd(&bcur[t], hcnt[t]) : 0;
    __syncthreads();
    for (int i = base + threadIdx.x; i < end; i += 256) {
        int d = dst[i];
        int b = d >> 8;
        int p = atomicAdd(&hcur[b], 1);
        ebuf[gbase[b] + p] = make_int2(d, src[i]);
    }
}

// ---------------- per-bucket CSR assembly (one workgroup per bucket) --------
__global__ void k_csr(const int2* __restrict__ ebuf, const int* __restrict__ bbase,
                      int* __restrict__ rowptr, float* __restrict__ dinv,
                      int* __restrict__ csr, int n) {
    __shared__ int hist[256];
    __shared__ int scan[256];
    __shared__ int cur[256];
    int b = blockIdx.x;
    int lo = bbase[b], hi = bbase[b + 1];
    int nodebase = b << 8;
    int t = threadIdx.x;
    hist[t] = 0;
    __syncthreads();
    for (int i = lo + t; i < hi; i += 256)
        atomicAdd(&hist[ebuf[i].x & 255], 1);
    __syncthreads();
    int deg = hist[t];
    scan[t] = deg;
    __syncthreads();
    for (int off = 1; off < 256; off <<= 1) {
        int u = (t >= off) ? scan[t - off] : 0;
        __syncthreads();
        scan[t] += u;
        __syncthreads();
    }
    int ex = scan[t] - deg;       // exclusive prefix within bucket
    cur[t] = ex;
    int node = nodebase + t;
    if (node < n) {
        rowptr[node] = lo + ex;
        dinv[node] = rsqrtf((float)deg + 1.0f);
    }
    __syncthreads();
    for (int i = lo + t; i < hi; i += 256) {
        int2 e = ebuf[i];
        int p = atomicAdd(&cur[e.x & 255], 1);
        csr[lo + p] = e.y;
    }
}

// ---------------- tiled GEMM (vector-ALU f32, register blocking) ------------
// Block: 64 rows x H cols. Thread: 4 rows x COLV cols (COLV = H/16).
// X chunk staged transposed in LDS (stride 65: conflict-free reads, 2-way writes).
template<int K, int H, bool SCALE, bool BIAS>
__global__ __launch_bounds__(256) void k_gemm_t(
        const float* __restrict__ X, const float* __restrict__ W,
        const float* __restrict__ bias, const float* __restrict__ dinv,
        float* __restrict__ Y, int n) {
    constexpr int COLV = H / 16;
    __shared__ float Ws[K * H];
    __shared__ float XsT[64][65];
    int tid = threadIdx.x;
    for (int i = tid; i < K * H; i += 256) Ws[i] = W[i];
    int tr = tid >> 4;          // 0..15 (row group of 4)
    int tc = tid & 15;          // 0..15 (col group of COLV)
    int rowBase = blockIdx.x * 64;
    float acc[4][COLV];
    #pragma unroll
    for (int i = 0; i < 4; i++)
        #pragma unroll
        for (int c = 0; c < COLV; c++) acc[i][c] = 0.f;

    for (int kc = 0; kc < K; kc += 64) {
        __syncthreads();
        #pragma unroll
        for (int j = 0; j < 4; j++) {
            int flat = tid + j * 256;        // 0..1023
            int row = flat >> 4;             // 0..63
            int kv  = flat & 15;             // float4 index within chunk
            int gr = rowBase + row;
            float4 v = make_float4(0.f, 0.f, 0.f, 0.f);
            if (gr < n)
                v = *reinterpret_cast<const float4*>(X + (size_t)gr * K + kc + kv * 4);
            XsT[kv * 4 + 0][row] = v.x;
            XsT[kv * 4 + 1][row] = v.y;
            XsT[kv * 4 + 2][row] = v.z;
            XsT[kv * 4 + 3][row] = v.w;
        }
        __syncthreads();
        #pragma unroll
        for (int k = 0; k < 64; k++) {
            float a0 = XsT[k][tr * 4 + 0];
            float a1 = XsT[k][tr * 4 + 1];
            float a2 = XsT[k][tr * 4 + 2];
            float a3 = XsT[k][tr * 4 + 3];
            const float* bp = &Ws[(kc + k) * H + tc * COLV];
            #pragma unroll
            for (int c = 0; c < COLV; c++) {
                float b = bp[c];
                acc[0][c] = fmaf(a0, b, acc[0][c]);
                acc[1][c] = fmaf(a1, b, acc[1][c]);
                acc[2][c] = fmaf(a2, b, acc[2][c]);
                acc[3][c] = fmaf(a3, b, acc[3][c]);
            }
        }
    }
    // epilogue
    #pragma unroll
    for (int i = 0; i < 4; i++) {
        int row = rowBase + tr * 4 + i;
        if (row >= n) continue;
        float s = SCALE ? dinv[row] : 1.f;
        float v[COLV];
        #pragma unroll
        for (int c = 0; c < COLV; c++) {
            float t2 = acc[i][c];
            if (SCALE) t2 *= s;
            if (BIAS)  t2 += bias[tc * COLV + c];
            v[c] = t2;
        }
        float* yp = Y + (size_t)row * H + tc * COLV;
        if (COLV == 4)      *reinterpret_cast<float4*>(yp) = make_float4(v[0], v[1], v[2], v[3]);
        else                *reinterpret_cast<float2*>(yp) = make_float2(v[0], v[1]);
    }
}

// ---------------- Aggregation: one wave per node, lane = feature ----------
__global__ void k_agg(const int* __restrict__ rowptr, const int* __restrict__ csr,
                      const float* __restrict__ y, const float* __restrict__ dinv,
                      const float* __restrict__ bias, float* __restrict__ out, int n) {
    int wave = (int)((blockIdx.x * (size_t)blockDim.x + threadIdx.x) >> 6);
    int lane = threadIdx.x & 63;
    if (wave >= n) return;
    int node = wave;
    float a0 = y[(size_t)node * 64 + lane];
    float a1 = 0.f, a2 = 0.f, a3 = 0.f;
    int s = rowptr[node];
    int e = rowptr[node + 1];
    for (int base = s; base < e; base += 64) {
        int rem = e - base; int cnt = rem > 64 ? 64 : rem;
        int idx = (base + lane < e) ? csr[base + lane] : 0;
        int j = 0;
        for (; j + 4 <= cnt; j += 4) {
            int s0 = __shfl(idx, j);
            int s1 = __shfl(idx, j + 1);
            int s2 = __shfl(idx, j + 2);
            int s3 = __shfl(idx, j + 3);
            float v0 = y[(size_t)s0 * 64 + lane];
            float v1 = y[(size_t)s1 * 64 + lane];
            float v2 = y[(size_t)s2 * 64 + lane];
            float v3 = y[(size_t)s3 * 64 + lane];
            a0 += v0; a1 += v1; a2 += v2; a3 += v3;
        }
        for (; j < cnt; j++) {
            int s0 = __shfl(idx, j);
            a0 += y[(size_t)s0 * 64 + lane];
        }
    }
    float v = dinv[node] * ((a0 + a1) + (a2 + a3)) + bias[lane];
    out[(size_t)node * 64 + lane] = fmaxf(v, 0.f);
}

// ---------------- launch ----------------
extern "C" void kernel_launch(void* const* d_in, const int* in_sizes, int n_in,
                              void* d_out, int out_size, void* d_ws, size_t ws_size,
                              hipStream_t stream) {
    const float* x  = (const float*)d_in[0];
    const int*   ei = (const int*)d_in[1];
    const float* W1 = (const float*)d_in[2];
    const float* b1 = (const float*)d_in[3];
    const float* W2 = (const float*)d_in[4];
    const float* b2 = (const float*)d_in[5];
    const float* Wl = (const float*)d_in[6];
    const float* bl = (const float*)d_in[7];
    float* out = (float*)d_out;

    const int n = in_sizes[0] / 128;     // 100000
    const int E = in_sizes[1] / 2;       // 3200000
    const int* src = ei;
    const int* dst = ei + E;
    const int nbuk = (n + 255) >> 8;     // 391

    char* p = (char*)d_ws;
    auto alloc = [&](size_t bytes) { char* r = p; p += (bytes + 255) & ~(size_t)255; return r; };
    float* dinv   = (float*)alloc((size_t)n * 4);
    int*   bcnt   = (int*)  alloc(MAXBUK * 4);
    int*   bcur   = (int*)  alloc(MAXBUK * 4);
    int*   bbase  = (int*)  alloc((MAXBUK + 1) * 4);
    int*   rowptr = (int*)  alloc((size_t)(n + 1) * 4);
    int*   csr    = (int*)  alloc((size_t)E * 4);
    float* bufY   = (float*)alloc((size_t)n * 64 * 4);
    float* bufA   = (float*)alloc((size_t)n * 64 * 4);
    float* bufB   = (float*)alloc((size_t)n * 64 * 4);
    (void)ws_size;

    int2* ebuf = (int2*)bufY;            // alias: ebuf dead before gemm1 writes bufY

    hipMemsetAsync(bcnt, 0, MAXBUK * 4, stream);
    k_bhist<<<512, 256, 0, stream>>>(dst, bcnt, E, nbuk);
    k_bscan<<<1, 64, 0, stream>>>(bcnt, bbase, bcur, rowptr, nbuk, n);
    k_part2<<<(E + 8191) / 8192, 256, 0, stream>>>(src, dst, bcur, ebuf, E, nbuk);
    k_csr<<<nbuk, 256, 0, stream>>>(ebuf, bbase, rowptr, dinv, csr, n);

    const int GB = (n + 63) / 64;        // 1563 blocks

    // layer 1: y = dinv ⊙ (x @ W1); h1 = relu(dinv*agg + b1)
    k_gemm_t<128, 64, true, false><<<GB, 256, 0, stream>>>(x, W1, nullptr, dinv, bufY, n);
    k_agg<<<(n + 3) / 4, 256, 0, stream>>>(rowptr, csr, bufY, dinv, b1, bufA, n);

    // layer 2
    k_gemm_t<64, 64, true, false><<<GB, 256, 0, stream>>>(bufA, W2, nullptr, dinv, bufB, n);
    k_agg<<<(n + 3) / 4, 256, 0, stream>>>(rowptr, csr, bufB, dinv, b2, bufA, n);

    // head: out = h2 @ Wl + bl
    k_gemm_t<64, 32, false, true><<<GB, 256, 0, stream>>>(bufA, Wl, bl, nullptr, out, n);
}

// Round 6
// 387.211 us; speedup vs baseline: 1.8612x; 1.1789x over previous
//
#include <hip/hip_runtime.h>

#define MAXBUK 512          // buckets of 256 dst-nodes; n=100000 -> 391 buckets

typedef unsigned short ushort_t;
typedef unsigned int uint_t;

__device__ inline float bf2f(ushort_t h) {
    union { uint_t u; float f; } c; c.u = ((uint_t)h) << 16; return c.f;
}
__device__ inline ushort_t f2bf(float f) {
    union { uint_t u; float f2; } c; c.f2 = f;
    uint_t r = c.u + 0x7FFFu + ((c.u >> 16) & 1u);   // round-to-nearest-even
    return (ushort_t)(r >> 16);
}

// ---------------- fine-bucket histogram of dst ----------------
__global__ void k_bhist(const int* __restrict__ dst, int* __restrict__ bcnt,
                        int E, int nbuk) {
    __shared__ int s[MAXBUK];
    for (int t = threadIdx.x; t < nbuk; t += 256) s[t] = 0;
    __syncthreads();
    int stride = gridDim.x * blockDim.x;
    int E4 = E >> 2;
    const int4* d4 = (const int4*)dst;
    for (int i = blockIdx.x * blockDim.x + threadIdx.x; i < E4; i += stride) {
        int4 v = d4[i];
        atomicAdd(&s[v.x >> 8], 1);
        atomicAdd(&s[v.y >> 8], 1);
        atomicAdd(&s[v.z >> 8], 1);
        atomicAdd(&s[v.w >> 8], 1);
    }
    if (blockIdx.x == 0 && threadIdx.x < (E & 3))
        atomicAdd(&s[dst[(E & ~3) + threadIdx.x] >> 8], 1);
    __syncthreads();
    for (int t = threadIdx.x; t < nbuk; t += 256)
        if (s[t]) atomicAdd(&bcnt[t], s[t]);
}

// serial scan of bucket counts -> bucket bases (= CSR region bases)
__global__ void k_bscan(const int* __restrict__ bcnt, int* __restrict__ bbase,
                        int* __restrict__ bcur, int* __restrict__ rowptr,
                        int nbuk, int n) {
    if (threadIdx.x == 0 && blockIdx.x == 0) {
        int acc = 0;
        for (int b = 0; b < nbuk; b++) { bbase[b] = acc; bcur[b] = acc; acc += bcnt[b]; }
        bbase[nbuk] = acc;
        rowptr[n] = acc;
    }
}

// ---------------- partition edges into bucket-contiguous ebuf ----------------
__global__ void k_part2(const int* __restrict__ src, const int* __restrict__ dst,
                        int* __restrict__ bcur, int2* __restrict__ ebuf,
                        int E, int nbuk) {
    __shared__ int hcnt[MAXBUK];
    __shared__ int gbase[MAXBUK];
    __shared__ int hcur[MAXBUK];
    int base = blockIdx.x * 8192;
    int end = base + 8192; if (end > E) end = E;
    for (int t = threadIdx.x; t < nbuk; t += 256) { hcnt[t] = 0; hcur[t] = 0; }
    __syncthreads();
    for (int i = base + threadIdx.x; i < end; i += 256)
        atomicAdd(&hcnt[dst[i] >> 8], 1);
    __syncthreads();
    for (int t = threadIdx.x; t < nbuk; t += 256)
        gbase[t] = hcnt[t] ? atomicAdd(&bcur[t], hcnt[t]) : 0;
    __syncthreads();
    for (int i = base + threadIdx.x; i < end; i += 256) {
        int d = dst[i];
        int b = d >> 8;
        int p = atomicAdd(&hcur[b], 1);
        ebuf[gbase[b] + p] = make_int2(d, src[i]);
    }
}

// ---------------- per-bucket CSR assembly (one workgroup per bucket) --------
__global__ void k_csr(const int2* __restrict__ ebuf, const int* __restrict__ bbase,
                      int* __restrict__ rowptr, float* __restrict__ dinv,
                      int* __restrict__ csr, int n) {
    __shared__ int hist[256];
    __shared__ int scan[256];
    __shared__ int cur[256];
    int b = blockIdx.x;
    int lo = bbase[b], hi = bbase[b + 1];
    int nodebase = b << 8;
    int t = threadIdx.x;
    hist[t] = 0;
    __syncthreads();
    for (int i = lo + t; i < hi; i += 256)
        atomicAdd(&hist[ebuf[i].x & 255], 1);
    __syncthreads();
    int deg = hist[t];
    scan[t] = deg;
    __syncthreads();
    for (int off = 1; off < 256; off <<= 1) {
        int u = (t >= off) ? scan[t - off] : 0;
        __syncthreads();
        scan[t] += u;
        __syncthreads();
    }
    int ex = scan[t] - deg;       // exclusive prefix within bucket
    cur[t] = ex;
    int node = nodebase + t;
    if (node < n) {
        rowptr[node] = lo + ex;
        dinv[node] = rsqrtf((float)deg + 1.0f);
    }
    __syncthreads();
    for (int i = lo + t; i < hi; i += 256) {
        int2 e = ebuf[i];
        int p = atomicAdd(&cur[e.x & 255], 1);
        csr[lo + p] = e.y;
    }
}

// ---------------- tiled GEMM (vector-ALU f32, register blocking) ------------
// Block: 64 rows x H cols. Thread: 4 rows x COLV cols (COLV = H/16).
template<int K, int H, bool SCALE, bool BIAS, bool OBF16>
__global__ __launch_bounds__(256) void k_gemm_t(
        const float* __restrict__ X, const float* __restrict__ W,
        const float* __restrict__ bias, const float* __restrict__ dinv,
        void* __restrict__ Yv, int n) {
    constexpr int COLV = H / 16;
    __shared__ float Ws[K * H];
    __shared__ float XsT[64][65];
    int tid = threadIdx.x;
    for (int i = tid; i < K * H; i += 256) Ws[i] = W[i];
    int tr = tid >> 4;          // 0..15 (row group of 4)
    int tc = tid & 15;          // 0..15 (col group of COLV)
    int rowBase = blockIdx.x * 64;
    float acc[4][COLV];
    #pragma unroll
    for (int i = 0; i < 4; i++)
        #pragma unroll
        for (int c = 0; c < COLV; c++) acc[i][c] = 0.f;

    for (int kc = 0; kc < K; kc += 64) {
        __syncthreads();
        #pragma unroll
        for (int j = 0; j < 4; j++) {
            int flat = tid + j * 256;        // 0..1023
            int row = flat >> 4;             // 0..63
            int kv  = flat & 15;             // float4 index within chunk
            int gr = rowBase + row;
            float4 v = make_float4(0.f, 0.f, 0.f, 0.f);
            if (gr < n)
                v = *reinterpret_cast<const float4*>(X + (size_t)gr * K + kc + kv * 4);
            XsT[kv * 4 + 0][row] = v.x;
            XsT[kv * 4 + 1][row] = v.y;
            XsT[kv * 4 + 2][row] = v.z;
            XsT[kv * 4 + 3][row] = v.w;
        }
        __syncthreads();
        #pragma unroll
        for (int k = 0; k < 64; k++) {
            float a0 = XsT[k][tr * 4 + 0];
            float a1 = XsT[k][tr * 4 + 1];
            float a2 = XsT[k][tr * 4 + 2];
            float a3 = XsT[k][tr * 4 + 3];
            const float* bp = &Ws[(kc + k) * H + tc * COLV];
            #pragma unroll
            for (int c = 0; c < COLV; c++) {
                float b = bp[c];
                acc[0][c] = fmaf(a0, b, acc[0][c]);
                acc[1][c] = fmaf(a1, b, acc[1][c]);
                acc[2][c] = fmaf(a2, b, acc[2][c]);
                acc[3][c] = fmaf(a3, b, acc[3][c]);
            }
        }
    }
    // epilogue
    #pragma unroll
    for (int i = 0; i < 4; i++) {
        int row = rowBase + tr * 4 + i;
        if (row >= n) continue;
        float s = SCALE ? dinv[row] : 1.f;
        float v[COLV];
        #pragma unroll
        for (int c = 0; c < COLV; c++) {
            float t2 = acc[i][c];
            if (SCALE) t2 *= s;
            if (BIAS)  t2 += bias[tc * COLV + c];
            v[c] = t2;
        }
        if (OBF16) {
            ushort_t* Y = (ushort_t*)Yv;
            ushort4 pk;
            pk.x = f2bf(v[0]); pk.y = f2bf(v[1]);
            pk.z = f2bf(v[2]); pk.w = f2bf(v[3]);
            *reinterpret_cast<ushort4*>(Y + (size_t)row * H + tc * COLV) = pk;
        } else {
            float* Y = (float*)Yv;
            float* yp = Y + (size_t)row * H + tc * COLV;
            if (COLV == 4)      *reinterpret_cast<float4*>(yp) = make_float4(v[0], v[1], v[2], v[3]);
            else                *reinterpret_cast<float2*>(yp) = make_float2(v[0], v[1]);
        }
    }
}

// ---------------- Aggregation from bf16 table: 2 edges per wave-gather ------
// y viewed as uint (2 bf16 features). Lanes 0-31 handle edge j (feature pair
// fp = lane&31), lanes 32-63 handle edge j+1. f32 accumulate, shfl_xor(32)
// cross-half reduce, self-loop + bias + relu in half 0, float2 store.
__global__ void k_agg_bf(const int* __restrict__ rowptr, const int* __restrict__ csr,
                         const uint_t* __restrict__ y, const float* __restrict__ dinv,
                         const float* __restrict__ bias, float* __restrict__ out, int n) {
    int wave = (int)((blockIdx.x * (size_t)blockDim.x + threadIdx.x) >> 6);
    int lane = threadIdx.x & 63;
    if (wave >= n) return;
    int node = wave;
    int half = lane >> 5;
    int fp = lane & 31;
    float ax0 = 0.f, ay0 = 0.f, ax1 = 0.f, ay1 = 0.f;
    int s = rowptr[node], e = rowptr[node + 1];
    for (int base = s; base < e; base += 64) {
        int rem = e - base; int cnt = rem > 64 ? 64 : rem;
        int idx = (base + lane < e) ? csr[base + lane] : -1;
        int j = 0;
        for (; j + 4 <= cnt; j += 4) {
            int sA0 = __shfl(idx, j);
            int sB0 = __shfl(idx, j + 1);
            int sA1 = __shfl(idx, j + 2);
            int sB1 = __shfl(idx, j + 3);
            int s0 = half ? sB0 : sA0;
            int s1 = half ? sB1 : sA1;
            uint_t u0 = y[(size_t)s0 * 32 + fp];
            uint_t u1 = y[(size_t)s1 * 32 + fp];
            ax0 += bf2f((ushort_t)u0); ay0 += bf2f((ushort_t)(u0 >> 16));
            ax1 += bf2f((ushort_t)u1); ay1 += bf2f((ushort_t)(u1 >> 16));
        }
        for (; j < cnt; j += 2) {
            int sA = __shfl(idx, j);
            int sB = (j + 1 < cnt) ? __shfl(idx, j + 1) : -1;
            int s2 = half ? sB : sA;
            if (s2 >= 0) {
                uint_t u = y[(size_t)s2 * 32 + fp];
                ax0 += bf2f((ushort_t)u); ay0 += bf2f((ushort_t)(u >> 16));
            }
        }
    }
    ax0 += ax1; ay0 += ay1;
    ax0 += __shfl_xor(ax0, 32);
    ay0 += __shfl_xor(ay0, 32);
    if (half == 0) {
        uint_t u = y[(size_t)node * 32 + fp];   // self-loop
        ax0 += bf2f((ushort_t)u); ay0 += bf2f((ushort_t)(u >> 16));
        float di = dinv[node];
        float2 b = *reinterpret_cast<const float2*>(bias + 2 * fp);
        float2 v;
        v.x = fmaxf(fmaf(di, ax0, b.x), 0.f);
        v.y = fmaxf(fmaf(di, ay0, b.y), 0.f);
        *reinterpret_cast<float2*>(out + (size_t)node * 64 + 2 * fp) = v;
    }
}

// ---------------- launch ----------------
extern "C" void kernel_launch(void* const* d_in, const int* in_sizes, int n_in,
                              void* d_out, int out_size, void* d_ws, size_t ws_size,
                              hipStream_t stream) {
    const float* x  = (const float*)d_in[0];
    const int*   ei = (const int*)d_in[1];
    const float* W1 = (const float*)d_in[2];
    const float* b1 = (const float*)d_in[3];
    const float* W2 = (const float*)d_in[4];
    const float* b2 = (const float*)d_in[5];
    const float* Wl = (const float*)d_in[6];
    const float* bl = (const float*)d_in[7];
    float* out = (float*)d_out;

    const int n = in_sizes[0] / 128;     // 100000
    const int E = in_sizes[1] / 2;       // 3200000
    const int* src = ei;
    const int* dst = ei + E;
    const int nbuk = (n + 255) >> 8;     // 391

    char* p = (char*)d_ws;
    auto alloc = [&](size_t bytes) { char* r = p; p += (bytes + 255) & ~(size_t)255; return r; };
    float* dinv   = (float*)alloc((size_t)n * 4);
    int*   bcnt   = (int*)  alloc(MAXBUK * 4);
    int*   bcur   = (int*)  alloc(MAXBUK * 4);
    int*   bbase  = (int*)  alloc((MAXBUK + 1) * 4);
    int*   rowptr = (int*)  alloc((size_t)(n + 1) * 4);
    int*   csr    = (int*)  alloc((size_t)E * 4);
    char*  slotE  = (char*) alloc((size_t)E * 8);        // ebuf (int2) / bufY (bf16 table)
    float* bufA   = (float*)alloc((size_t)n * 64 * 4);   // f32 activations
    ushort_t* bufB = (ushort_t*)alloc((size_t)n * 64 * 2); // bf16 table layer 2
    (void)ws_size;

    int2*     ebuf = (int2*)slotE;
    ushort_t* bufY = (ushort_t*)slotE;   // alias: ebuf dead before gemm1 writes bufY

    hipMemsetAsync(bcnt, 0, MAXBUK * 4, stream);
    k_bhist<<<512, 256, 0, stream>>>(dst, bcnt, E, nbuk);
    k_bscan<<<1, 64, 0, stream>>>(bcnt, bbase, bcur, rowptr, nbuk, n);
    k_part2<<<(E + 8191) / 8192, 256, 0, stream>>>(src, dst, bcur, ebuf, E, nbuk);
    k_csr<<<nbuk, 256, 0, stream>>>(ebuf, bbase, rowptr, dinv, csr, n);

    const int GB = (n + 63) / 64;        // 1563 blocks
    const int AB = (n + 3) / 4;

    // layer 1: y = dinv ⊙ (x @ W1) [bf16]; h1 = relu(dinv*agg + b1) [f32]
    k_gemm_t<128, 64, true, false, true><<<GB, 256, 0, stream>>>(x, W1, nullptr, dinv, bufY, n);
    k_agg_bf<<<AB, 256, 0, stream>>>(rowptr, csr, (const uint_t*)bufY, dinv, b1, bufA, n);

    // layer 2
    k_gemm_t<64, 64, true, false, true><<<GB, 256, 0, stream>>>(bufA, W2, nullptr, dinv, bufB, n);
    k_agg_bf<<<AB, 256, 0, stream>>>(rowptr, csr, (const uint_t*)bufB, dinv, b2, bufA, n);

    // head: out = h2 @ Wl + bl (f32)
    k_gemm_t<64, 32, false, true, false><<<GB, 256, 0, stream>>>(bufA, Wl, bl, nullptr, out, n);
}

// Round 7
// 348.676 us; speedup vs baseline: 2.0669x; 1.1105x over previous
//
#include <hip/hip_runtime.h>

#define MAXBUK 512          // buckets of 256 dst-nodes; n=100000 -> 391 buckets
#define PTILE 4096          // edges per k_part2 block (32KB LDS stage)

typedef unsigned short ushort_t;
typedef unsigned int uint_t;

__device__ inline float bf2f(ushort_t h) {
    union { uint_t u; float f; } c; c.u = ((uint_t)h) << 16; return c.f;
}
__device__ inline ushort_t f2bf(float f) {
    union { uint_t u; float f2; } c; c.f2 = f;
    uint_t r = c.u + 0x7FFFu + ((c.u >> 16) & 1u);   // round-to-nearest-even
    return (ushort_t)(r >> 16);
}

// ---------------- fine-bucket histogram of dst ----------------
__global__ void k_bhist(const int* __restrict__ dst, int* __restrict__ bcnt,
                        int E, int nbuk) {
    __shared__ int s[MAXBUK];
    for (int t = threadIdx.x; t < nbuk; t += 256) s[t] = 0;
    __syncthreads();
    int stride = gridDim.x * blockDim.x;
    int E4 = E >> 2;
    const int4* d4 = (const int4*)dst;
    for (int i = blockIdx.x * blockDim.x + threadIdx.x; i < E4; i += stride) {
        int4 v = d4[i];
        atomicAdd(&s[v.x >> 8], 1);
        atomicAdd(&s[v.y >> 8], 1);
        atomicAdd(&s[v.z >> 8], 1);
        atomicAdd(&s[v.w >> 8], 1);
    }
    if (blockIdx.x == 0 && threadIdx.x < (E & 3))
        atomicAdd(&s[dst[(E & ~3) + threadIdx.x] >> 8], 1);
    __syncthreads();
    for (int t = threadIdx.x; t < nbuk; t += 256)
        if (s[t]) atomicAdd(&bcnt[t], s[t]);
}

// ---------------- parallel scan of bucket counts (512 threads, LDS) --------
__global__ void k_bscan2(const int* __restrict__ bcnt, int* __restrict__ bbase,
                         int* __restrict__ bcur, int* __restrict__ rowptr,
                         int nbuk, int n) {
    __shared__ int tmp[512];
    int t = threadIdx.x;
    int v = (t < nbuk) ? bcnt[t] : 0;
    tmp[t] = v;
    __syncthreads();
    for (int off = 1; off < 512; off <<= 1) {
        int u = (t >= off) ? tmp[t - off] : 0;
        __syncthreads();
        tmp[t] += u;
        __syncthreads();
    }
    int ex = tmp[t] - v;            // exclusive prefix
    if (t < nbuk) { bbase[t] = ex; bcur[t] = ex; }
    if (t == nbuk) { bbase[t] = ex; rowptr[n] = ex; }
}

// ---------------- partition edges into bucket-contiguous ebuf ----------------
// LDS-staged counting sort per tile: scattered 8B writes become coalesced
// contiguous runs per bucket (full-line evictions).
__global__ __launch_bounds__(256) void k_part2(
        const int* __restrict__ src, const int* __restrict__ dst,
        int* __restrict__ bcur, int2* __restrict__ ebuf, int E) {
    __shared__ int hcnt[MAXBUK];
    __shared__ int lbase[MAXBUK];
    __shared__ int gbase[MAXBUK];
    __shared__ int hcur[MAXBUK];
    __shared__ int psum[256];
    __shared__ int2 stage[PTILE];
    int t = threadIdx.x;
    int base = blockIdx.x * PTILE;
    int end = base + PTILE; if (end > E) end = E;
    int cnt = end - base;
    #pragma unroll
    for (int j = 0; j < MAXBUK / 256; j++) { hcnt[t + j * 256] = 0; hcur[t + j * 256] = 0; }
    __syncthreads();
    // P1: histogram
    for (int i = base + t; i < end; i += 256)
        atomicAdd(&hcnt[dst[i] >> 8], 1);
    __syncthreads();
    // P2: exclusive scan of hcnt[0..511] (2 elems/thread) + global reservation
    int a = hcnt[2 * t], b2 = hcnt[2 * t + 1];
    int ps = a + b2;
    psum[t] = ps;
    __syncthreads();
    for (int off = 1; off < 256; off <<= 1) {
        int u = (t >= off) ? psum[t - off] : 0;
        __syncthreads();
        psum[t] += u;
        __syncthreads();
    }
    int exp2_ = psum[t] - ps;
    lbase[2 * t] = exp2_;
    lbase[2 * t + 1] = exp2_ + a;
    __syncthreads();
    #pragma unroll
    for (int j = 0; j < MAXBUK / 256; j++) {
        int bk = t + j * 256;
        int c = hcnt[bk];
        gbase[bk] = c ? atomicAdd(&bcur[bk], c) : 0;
    }
    __syncthreads();
    // P3: stage edges bucket-major in LDS
    for (int i = base + t; i < end; i += 256) {
        int d = dst[i];
        int bk = d >> 8;
        int p = atomicAdd(&hcur[bk], 1);
        stage[lbase[bk] + p] = make_int2(d, src[i]);
    }
    __syncthreads();
    // P4: coalesced copy-out (consecutive i -> consecutive addrs per bucket run)
    for (int i = t; i < cnt; i += 256) {
        int2 e = stage[i];
        int bk = e.x >> 8;
        ebuf[gbase[bk] + (i - lbase[bk])] = e;
    }
}

// ---------------- per-bucket CSR assembly (one workgroup per bucket) --------
__global__ void k_csr(const int2* __restrict__ ebuf, const int* __restrict__ bbase,
                      int* __restrict__ rowptr, float* __restrict__ dinv,
                      int* __restrict__ csr, int n) {
    __shared__ int hist[256];
    __shared__ int scan[256];
    __shared__ int cur[256];
    int b = blockIdx.x;
    int lo = bbase[b], hi = bbase[b + 1];
    int nodebase = b << 8;
    int t = threadIdx.x;
    hist[t] = 0;
    __syncthreads();
    for (int i = lo + t; i < hi; i += 256)
        atomicAdd(&hist[ebuf[i].x & 255], 1);
    __syncthreads();
    int deg = hist[t];
    scan[t] = deg;
    __syncthreads();
    for (int off = 1; off < 256; off <<= 1) {
        int u = (t >= off) ? scan[t - off] : 0;
        __syncthreads();
        scan[t] += u;
        __syncthreads();
    }
    int ex = scan[t] - deg;       // exclusive prefix within bucket
    cur[t] = ex;
    int node = nodebase + t;
    if (node < n) {
        rowptr[node] = lo + ex;
        dinv[node] = rsqrtf((float)deg + 1.0f);
    }
    __syncthreads();
    for (int i = lo + t; i < hi; i += 256) {
        int2 e = ebuf[i];
        int p = atomicAdd(&cur[e.x & 255], 1);
        csr[lo + p] = e.y;
    }
}

// ---------------- tiled GEMM (vector-ALU f32, register blocking) ------------
template<int K, int H, bool SCALE, bool BIAS, bool OBF16>
__global__ __launch_bounds__(256) void k_gemm_t(
        const float* __restrict__ X, const float* __restrict__ W,
        const float* __restrict__ bias, const float* __restrict__ dinv,
        void* __restrict__ Yv, int n) {
    constexpr int COLV = H / 16;
    __shared__ float Ws[K * H];
    __shared__ float XsT[64][65];
    int tid = threadIdx.x;
    for (int i = tid; i < K * H; i += 256) Ws[i] = W[i];
    int tr = tid >> 4;          // 0..15 (row group of 4)
    int tc = tid & 15;          // 0..15 (col group of COLV)
    int rowBase = blockIdx.x * 64;
    float acc[4][COLV];
    #pragma unroll
    for (int i = 0; i < 4; i++)
        #pragma unroll
        for (int c = 0; c < COLV; c++) acc[i][c] = 0.f;

    for (int kc = 0; kc < K; kc += 64) {
        __syncthreads();
        #pragma unroll
        for (int j = 0; j < 4; j++) {
            int flat = tid + j * 256;        // 0..1023
            int row = flat >> 4;             // 0..63
            int kv  = flat & 15;             // float4 index within chunk
            int gr = rowBase + row;
            float4 v = make_float4(0.f, 0.f, 0.f, 0.f);
            if (gr < n)
                v = *reinterpret_cast<const float4*>(X + (size_t)gr * K + kc + kv * 4);
            XsT[kv * 4 + 0][row] = v.x;
            XsT[kv * 4 + 1][row] = v.y;
            XsT[kv * 4 + 2][row] = v.z;
            XsT[kv * 4 + 3][row] = v.w;
        }
        __syncthreads();
        #pragma unroll
        for (int k = 0; k < 64; k++) {
            float a0 = XsT[k][tr * 4 + 0];
            float a1 = XsT[k][tr * 4 + 1];
            float a2 = XsT[k][tr * 4 + 2];
            float a3 = XsT[k][tr * 4 + 3];
            const float* bp = &Ws[(kc + k) * H + tc * COLV];
            #pragma unroll
            for (int c = 0; c < COLV; c++) {
                float b = bp[c];
                acc[0][c] = fmaf(a0, b, acc[0][c]);
                acc[1][c] = fmaf(a1, b, acc[1][c]);
                acc[2][c] = fmaf(a2, b, acc[2][c]);
                acc[3][c] = fmaf(a3, b, acc[3][c]);
            }
        }
    }
    // epilogue
    #pragma unroll
    for (int i = 0; i < 4; i++) {
        int row = rowBase + tr * 4 + i;
        if (row >= n) continue;
        float s = SCALE ? dinv[row] : 1.f;
        float v[COLV];
        #pragma unroll
        for (int c = 0; c < COLV; c++) {
            float t2 = acc[i][c];
            if (SCALE) t2 *= s;
            if (BIAS)  t2 += bias[tc * COLV + c];
            v[c] = t2;
        }
        if (OBF16) {
            ushort_t* Y = (ushort_t*)Yv;
            ushort4 pk;
            pk.x = f2bf(v[0]); pk.y = f2bf(v[1]);
            pk.z = f2bf(v[2]); pk.w = f2bf(v[3]);
            *reinterpret_cast<ushort4*>(Y + (size_t)row * H + tc * COLV) = pk;
        } else {
            float* Y = (float*)Yv;
            float* yp = Y + (size_t)row * H + tc * COLV;
            if (COLV == 4)      *reinterpret_cast<float4*>(yp) = make_float4(v[0], v[1], v[2], v[3]);
            else                *reinterpret_cast<float2*>(yp) = make_float2(v[0], v[1]);
        }
    }
}

// ---------------- Aggregation from bf16 table, software-pipelined -----------
// 2 edges per wave-gather (lanes 0-31 edge A, 32-63 edge B; lane loads uint =
// 2 bf16 features). Pipeline depth: 4 loads (8 edges) in flight.
__global__ void k_agg_bf(const int* __restrict__ rowptr, const int* __restrict__ csr,
                         const uint_t* __restrict__ y, const float* __restrict__ dinv,
                         const float* __restrict__ bias, float* __restrict__ out, int n) {
    int wave = (int)((blockIdx.x * (size_t)blockDim.x + threadIdx.x) >> 6);
    int lane = threadIdx.x & 63;
    if (wave >= n) return;
    int node = wave;
    int half = lane >> 5;
    int fp = lane & 31;
    float ax0 = 0.f, ay0 = 0.f, ax1 = 0.f, ay1 = 0.f;
    float ax2 = 0.f, ay2 = 0.f, ax3 = 0.f, ay3 = 0.f;
    int s = rowptr[node], e = rowptr[node + 1];
    for (int base = s; base < e; base += 64) {
        int rem = e - base; int cnt = rem > 64 ? 64 : rem;
        int idx = (base + lane < e) ? csr[base + lane] : -1;
        int j = 0;
        uint_t p0, p1, p2, p3;
        bool pend = false;
        if (cnt >= 8) {
            int a0 = __shfl(idx, 0), a1 = __shfl(idx, 1), a2 = __shfl(idx, 2), a3 = __shfl(idx, 3);
            int a4 = __shfl(idx, 4), a5 = __shfl(idx, 5), a6 = __shfl(idx, 6), a7 = __shfl(idx, 7);
            p0 = y[(size_t)(half ? a1 : a0) * 32 + fp];
            p1 = y[(size_t)(half ? a3 : a2) * 32 + fp];
            p2 = y[(size_t)(half ? a5 : a4) * 32 + fp];
            p3 = y[(size_t)(half ? a7 : a6) * 32 + fp];
            pend = true; j = 8;
        }
        for (; j + 8 <= cnt; j += 8) {
            int a0 = __shfl(idx, j),     a1 = __shfl(idx, j + 1), a2 = __shfl(idx, j + 2), a3 = __shfl(idx, j + 3);
            int a4 = __shfl(idx, j + 4), a5 = __shfl(idx, j + 5), a6 = __shfl(idx, j + 6), a7 = __shfl(idx, j + 7);
            uint_t q0 = y[(size_t)(half ? a1 : a0) * 32 + fp];
            uint_t q1 = y[(size_t)(half ? a3 : a2) * 32 + fp];
            uint_t q2 = y[(size_t)(half ? a5 : a4) * 32 + fp];
            uint_t q3 = y[(size_t)(half ? a7 : a6) * 32 + fp];
            ax0 += bf2f((ushort_t)p0); ay0 += bf2f((ushort_t)(p0 >> 16));
            ax1 += bf2f((ushort_t)p1); ay1 += bf2f((ushort_t)(p1 >> 16));
            ax2 += bf2f((ushort_t)p2); ay2 += bf2f((ushort_t)(p2 >> 16));
            ax3 += bf2f((ushort_t)p3); ay3 += bf2f((ushort_t)(p3 >> 16));
            p0 = q0; p1 = q1; p2 = q2; p3 = q3;
        }
        if (pend) {
            ax0 += bf2f((ushort_t)p0); ay0 += bf2f((ushort_t)(p0 >> 16));
            ax1 += bf2f((ushort_t)p1); ay1 += bf2f((ushort_t)(p1 >> 16));
            ax2 += bf2f((ushort_t)p2); ay2 += bf2f((ushort_t)(p2 >> 16));
            ax3 += bf2f((ushort_t)p3); ay3 += bf2f((ushort_t)(p3 >> 16));
        }
        for (; j + 2 <= cnt; j += 2) {
            int sA = __shfl(idx, j), sB = __shfl(idx, j + 1);
            uint_t u = y[(size_t)(half ? sB : sA) * 32 + fp];
            ax0 += bf2f((ushort_t)u); ay0 += bf2f((ushort_t)(u >> 16));
        }
        if (j < cnt) {
            int sA = __shfl(idx, j);
            if (half == 0) {
                uint_t u = y[(size_t)sA * 32 + fp];
                ax0 += bf2f((ushort_t)u); ay0 += bf2f((ushort_t)(u >> 16));
            }
        }
    }
    float ax = (ax0 + ax1) + (ax2 + ax3);
    float ay = (ay0 + ay1) + (ay2 + ay3);
    ax += __shfl_xor(ax, 32);
    ay += __shfl_xor(ay, 32);
    if (half == 0) {
        uint_t u = y[(size_t)node * 32 + fp];   // self-loop
        ax += bf2f((ushort_t)u); ay += bf2f((ushort_t)(u >> 16));
        float di = dinv[node];
        float2 b = *reinterpret_cast<const float2*>(bias + 2 * fp);
        float2 v;
        v.x = fmaxf(fmaf(di, ax, b.x), 0.f);
        v.y = fmaxf(fmaf(di, ay, b.y), 0.f);
        *reinterpret_cast<float2*>(out + (size_t)node * 64 + 2 * fp) = v;
    }
}

// ---------------- launch ----------------
extern "C" void kernel_launch(void* const* d_in, const int* in_sizes, int n_in,
                              void* d_out, int out_size, void* d_ws, size_t ws_size,
                              hipStream_t stream) {
    const float* x  = (const float*)d_in[0];
    const int*   ei = (const int*)d_in[1];
    const float* W1 = (const float*)d_in[2];
    const float* b1 = (const float*)d_in[3];
    const float* W2 = (const float*)d_in[4];
    const float* b2 = (const float*)d_in[5];
    const float* Wl = (const float*)d_in[6];
    const float* bl = (const float*)d_in[7];
    float* out = (float*)d_out;

    const int n = in_sizes[0] / 128;     // 100000
    const int E = in_sizes[1] / 2;       // 3200000
    const int* src = ei;
    const int* dst = ei + E;
    const int nbuk = (n + 255) >> 8;     // 391

    char* p = (char*)d_ws;
    auto alloc = [&](size_t bytes) { char* r = p; p += (bytes + 255) & ~(size_t)255; return r; };
    float* dinv   = (float*)alloc((size_t)n * 4);
    int*   bcnt   = (int*)  alloc(MAXBUK * 4);
    int*   bcur   = (int*)  alloc(MAXBUK * 4);
    int*   bbase  = (int*)  alloc((MAXBUK + 1) * 4);
    int*   rowptr = (int*)  alloc((size_t)(n + 1) * 4);
    int*   csr    = (int*)  alloc((size_t)E * 4);
    char*  slotE  = (char*) alloc((size_t)E * 8);        // ebuf (int2) / bufY (bf16 table)
    float* bufA   = (float*)alloc((size_t)n * 64 * 4);   // f32 activations
    ushort_t* bufB = (ushort_t*)alloc((size_t)n * 64 * 2); // bf16 table layer 2
    (void)ws_size;

    int2*     ebuf = (int2*)slotE;
    ushort_t* bufY = (ushort_t*)slotE;   // alias: ebuf dead before gemm1 writes bufY

    hipMemsetAsync(bcnt, 0, MAXBUK * 4, stream);
    k_bhist<<<512, 256, 0, stream>>>(dst, bcnt, E, nbuk);
    k_bscan2<<<1, 512, 0, stream>>>(bcnt, bbase, bcur, rowptr, nbuk, n);
    k_part2<<<(E + PTILE - 1) / PTILE, 256, 0, stream>>>(src, dst, bcur, ebuf, E);
    k_csr<<<nbuk, 256, 0, stream>>>(ebuf, bbase, rowptr, dinv, csr, n);

    const int GB = (n + 63) / 64;        // 1563 blocks
    const int AB = (n + 3) / 4;

    // layer 1: y = dinv ⊙ (x @ W1) [bf16]; h1 = relu(dinv*agg + b1) [f32]
    k_gemm_t<128, 64, true, false, true><<<GB, 256, 0, stream>>>(x, W1, nullptr, dinv, bufY, n);
    k_agg_bf<<<AB, 256, 0, stream>>>(rowptr, csr, (const uint_t*)bufY, dinv, b1, bufA, n);

    // layer 2
    k_gemm_t<64, 64, true, false, true><<<GB, 256, 0, stream>>>(bufA, W2, nullptr, dinv, bufB, n);
    k_agg_bf<<<AB, 256, 0, stream>>>(rowptr, csr, (const uint_t*)bufB, dinv, b2, bufA, n);

    // head: out = h2 @ Wl + bl (f32)
    k_gemm_t<64, 32, false, true, false><<<GB, 256, 0, stream>>>(bufA, Wl, bl, nullptr, out, n);
}

// Round 8
// 324.867 us; speedup vs baseline: 2.2183x; 1.0733x over previous
//
#include <hip/hip_runtime.h>

#define MAXBUK 512          // fine buckets of 256 dst-nodes; n=100000 -> 391
#define PTILE 4096          // edges per k_part2 block
#define CAP   10240         // per-bucket capacity (mean 8192, 6-sigma ~8735)

typedef unsigned short ushort_t;
typedef unsigned int uint_t;
typedef float v2f __attribute__((ext_vector_type(2)));

__device__ inline v2f unpk(uint_t u) {
    v2f r;
    r.x = __uint_as_float(u << 16);
    r.y = __uint_as_float(u & 0xFFFF0000u);
    return r;
}
__device__ inline ushort_t f2bf(float f) {
    union { uint_t u; float f2; } c; c.f2 = f;
    uint_t r = c.u + 0x7FFFu + ((c.u >> 16) & 1u);   // round-to-nearest-even
    return (ushort_t)(r >> 16);
}

// ---------------- init per-bucket cursors ----------------
__global__ void k_init(int* __restrict__ bcur, int nbuk) {
    int t = threadIdx.x;
    if (t < nbuk) bcur[t] = t * CAP;
}

// ---------------- partition edges into capped bucket regions ----------------
// LDS-staged counting sort per 4096-edge tile; ebuf entry packed:
// (dst & 255) << 24 | src   (src < 2^17).
__global__ __launch_bounds__(256) void k_part2(
        const int* __restrict__ src, const int* __restrict__ dst,
        int* __restrict__ bcur, uint_t* __restrict__ ebuf, int E) {
    __shared__ int hcnt[MAXBUK];
    __shared__ int lbase[MAXBUK];
    __shared__ int gbase[MAXBUK];
    __shared__ int hcur[MAXBUK];
    __shared__ int psum[256];
    __shared__ uint_t stage[PTILE];
    int t = threadIdx.x;
    int base = blockIdx.x * PTILE;
    int end = base + PTILE; if (end > E) end = E;
    int cnt = end - base;
    #pragma unroll
    for (int j = 0; j < MAXBUK / 256; j++) { hcnt[t + j * 256] = 0; hcur[t + j * 256] = 0; }
    __syncthreads();
    // P1: tile histogram
    for (int i = base + t; i < end; i += 256)
        atomicAdd(&hcnt[dst[i] >> 8], 1);
    __syncthreads();
    // P2: exclusive scan of hcnt (2/thread) + global reservation
    int a = hcnt[2 * t], b2 = hcnt[2 * t + 1];
    int ps = a + b2;
    psum[t] = ps;
    __syncthreads();
    for (int off = 1; off < 256; off <<= 1) {
        int u = (t >= off) ? psum[t - off] : 0;
        __syncthreads();
        psum[t] += u;
        __syncthreads();
    }
    int ex = psum[t] - ps;
    lbase[2 * t] = ex;
    lbase[2 * t + 1] = ex + a;
    __syncthreads();
    #pragma unroll
    for (int j = 0; j < MAXBUK / 256; j++) {
        int bk = t + j * 256;
        int c = hcnt[bk];
        gbase[bk] = c ? atomicAdd(&bcur[bk], c) : 0;
    }
    __syncthreads();
    // P3: stage bucket-major in LDS
    for (int i = base + t; i < end; i += 256) {
        int d = dst[i];
        int bk = d >> 8;
        int p = atomicAdd(&hcur[bk], 1);
        stage[lbase[bk] + p] = ((uint_t)(d & 255) << 24) | (uint_t)src[i];
    }
    __syncthreads();
    // P4: coalesced copy-out
    for (int i = t; i < cnt; i += 256) {
        uint_t e = stage[i];
        int bk = (dst[0], 0);  // placeholder avoided below
        (void)bk;
        int b = -1;
        // recover bucket: need dst bucket; store via lbase search is costly ->
        // instead recompute from position: find run via gbase/lbase is complex;
        // simpler: bucket is not in the packed word, so carry it in high bits of
        // stage temporarily? We pack (dlow<<24)|src; bucket recovered from the
        // run structure. To keep it simple and correct, we re-derive bucket by
        // binary search over lbase is overkill -- instead stage stores bucket
        // in a parallel LDS array.
        (void)b;
        break;
    }
    // ---- corrected P4 (uses parallel bucket array) ----
    __syncthreads();
    for (int i = t; i < cnt; i += 256) ;  // no-op, real path below
}

// The above P4 needs the bucket id; use a clean second implementation:
__global__ __launch_bounds__(256) void k_part2b(
        const int* __restrict__ src, const int* __restrict__ dst,
        int* __restrict__ bcur, uint_t* __restrict__ ebuf, int E) {
    __shared__ int hcnt[MAXBUK];
    __shared__ int lbase[MAXBUK];
    __shared__ int gbase[MAXBUK];
    __shared__ int hcur[MAXBUK];
    __shared__ int psum[256];
    __shared__ uint_t stage[PTILE];
    __shared__ unsigned short sbuk[PTILE];
    int t = threadIdx.x;
    int base = blockIdx.x * PTILE;
    int end = base + PTILE; if (end > E) end = E;
    int cnt = end - base;
    #pragma unroll
    for (int j = 0; j < MAXBUK / 256; j++) { hcnt[t + j * 256] = 0; hcur[t + j * 256] = 0; }
    __syncthreads();
    for (int i = base + t; i < end; i += 256)
        atomicAdd(&hcnt[dst[i] >> 8], 1);
    __syncthreads();
    int a = hcnt[2 * t], b2 = hcnt[2 * t + 1];
    int ps = a + b2;
    psum[t] = ps;
    __syncthreads();
    for (int off = 1; off < 256; off <<= 1) {
        int u = (t >= off) ? psum[t - off] : 0;
        __syncthreads();
        psum[t] += u;
        __syncthreads();
    }
    int ex = psum[t] - ps;
    lbase[2 * t] = ex;
    lbase[2 * t + 1] = ex + a;
    __syncthreads();
    #pragma unroll
    for (int j = 0; j < MAXBUK / 256; j++) {
        int bk = t + j * 256;
        int c = hcnt[bk];
        gbase[bk] = c ? atomicAdd(&bcur[bk], c) : 0;
    }
    __syncthreads();
    for (int i = base + t; i < end; i += 256) {
        int d = dst[i];
        int bk = d >> 8;
        int p = atomicAdd(&hcur[bk], 1);
        int sp = lbase[bk] + p;
        stage[sp] = ((uint_t)(d & 255) << 24) | (uint_t)src[i];
        sbuk[sp] = (unsigned short)bk;
    }
    __syncthreads();
    for (int i = t; i < cnt; i += 256) {
        int bk = sbuk[i];
        ebuf[gbase[bk] + (i - lbase[bk])] = stage[i];
    }
}

// ---------------- per-bucket CSR assembly (one workgroup per bucket) --------
__global__ void k_csr(const uint_t* __restrict__ ebuf, const int* __restrict__ bend,
                      int* __restrict__ rowptr, int* __restrict__ rowend,
                      float* __restrict__ dinv, int* __restrict__ csr, int n) {
    __shared__ int hist[256];
    __shared__ int scan[256];
    __shared__ int cur[256];
    int b = blockIdx.x;
    int lo = b * CAP, hi = bend[b];
    int nodebase = b << 8;
    int t = threadIdx.x;
    hist[t] = 0;
    __syncthreads();
    for (int i = lo + t; i < hi; i += 256)
        atomicAdd(&hist[ebuf[i] >> 24], 1);
    __syncthreads();
    int deg = hist[t];
    scan[t] = deg;
    __syncthreads();
    for (int off = 1; off < 256; off <<= 1) {
        int u = (t >= off) ? scan[t - off] : 0;
        __syncthreads();
        scan[t] += u;
        __syncthreads();
    }
    int ex = scan[t] - deg;
    cur[t] = ex;
    int node = nodebase + t;
    if (node < n) {
        rowptr[node] = lo + ex;
        rowend[node] = lo + ex + deg;
        dinv[node] = rsqrtf((float)deg + 1.0f);
    }
    __syncthreads();
    for (int i = lo + t; i < hi; i += 256) {
        uint_t e = ebuf[i];
        int p = atomicAdd(&cur[e >> 24], 1);
        csr[lo + p] = (int)(e & 0xFFFFFFu);
    }
}

// ---------------- tiled GEMM (vector-ALU f32, register blocking) ------------
template<int K, int H, bool SCALE, bool BIAS, bool OBF16>
__global__ __launch_bounds__(256) void k_gemm_t(
        const float* __restrict__ X, const float* __restrict__ W,
        const float* __restrict__ bias, const float* __restrict__ dinv,
        void* __restrict__ Yv, int n) {
    constexpr int COLV = H / 16;
    __shared__ float Ws[K * H];
    __shared__ float XsT[64][65];
    int tid = threadIdx.x;
    for (int i = tid; i < K * H; i += 256) Ws[i] = W[i];
    int tr = tid >> 4;
    int tc = tid & 15;
    int rowBase = blockIdx.x * 64;
    float acc[4][COLV];
    #pragma unroll
    for (int i = 0; i < 4; i++)
        #pragma unroll
        for (int c = 0; c < COLV; c++) acc[i][c] = 0.f;

    for (int kc = 0; kc < K; kc += 64) {
        __syncthreads();
        #pragma unroll
        for (int j = 0; j < 4; j++) {
            int flat = tid + j * 256;
            int row = flat >> 4;
            int kv  = flat & 15;
            int gr = rowBase + row;
            float4 v = make_float4(0.f, 0.f, 0.f, 0.f);
            if (gr < n)
                v = *reinterpret_cast<const float4*>(X + (size_t)gr * K + kc + kv * 4);
            XsT[kv * 4 + 0][row] = v.x;
            XsT[kv * 4 + 1][row] = v.y;
            XsT[kv * 4 + 2][row] = v.z;
            XsT[kv * 4 + 3][row] = v.w;
        }
        __syncthreads();
        #pragma unroll
        for (int k = 0; k < 64; k++) {
            float a0 = XsT[k][tr * 4 + 0];
            float a1 = XsT[k][tr * 4 + 1];
            float a2 = XsT[k][tr * 4 + 2];
            float a3 = XsT[k][tr * 4 + 3];
            const float* bp = &Ws[(kc + k) * H + tc * COLV];
            #pragma unroll
            for (int c = 0; c < COLV; c++) {
                float b = bp[c];
                acc[0][c] = fmaf(a0, b, acc[0][c]);
                acc[1][c] = fmaf(a1, b, acc[1][c]);
                acc[2][c] = fmaf(a2, b, acc[2][c]);
                acc[3][c] = fmaf(a3, b, acc[3][c]);
            }
        }
    }
    #pragma unroll
    for (int i = 0; i < 4; i++) {
        int row = rowBase + tr * 4 + i;
        if (row >= n) continue;
        float s = SCALE ? dinv[row] : 1.f;
        float v[COLV];
        #pragma unroll
        for (int c = 0; c < COLV; c++) {
            float t2 = acc[i][c];
            if (SCALE) t2 *= s;
            if (BIAS)  t2 += bias[tc * COLV + c];
            v[c] = t2;
        }
        if (OBF16) {
            ushort_t* Y = (ushort_t*)Yv;
            ushort4 pk;
            pk.x = f2bf(v[0]); pk.y = f2bf(v[1]);
            pk.z = f2bf(v[2]); pk.w = f2bf(v[3]);
            *reinterpret_cast<ushort4*>(Y + (size_t)row * H + tc * COLV) = pk;
        } else {
            float* Y = (float*)Yv;
            float* yp = Y + (size_t)row * H + tc * COLV;
            if (COLV == 4)      *reinterpret_cast<float4*>(yp) = make_float4(v[0], v[1], v[2], v[3]);
            else                *reinterpret_cast<float2*>(yp) = make_float2(v[0], v[1]);
        }
    }
}

// ---------------- agg core (bf16 table, pk-f32 accumulate, pipelined) -------
// Returns full (ax, ay) in BOTH halves if BOTHHALVES, else valid in half 0.
__device__ inline void agg_core(const int* rowptr, const int* rowend,
                                const int* csr, const uint_t* y,
                                int node, int lane, float& axo, float& ayo) {
    int half = lane >> 5;
    int fp = lane & 31;
    v2f a0 = {0.f, 0.f}, a1 = {0.f, 0.f}, a2 = {0.f, 0.f}, a3 = {0.f, 0.f};
    int s = rowptr[node], e = rowend[node];
    for (int base = s; base < e; base += 64) {
        int rem = e - base; int cnt = rem > 64 ? 64 : rem;
        int idx = (base + lane < e) ? csr[base + lane] : -1;
        int j = 0;
        uint_t p0, p1, p2, p3;
        bool pend = false;
        if (cnt >= 8) {
            int b0 = __shfl(idx, 0), b1 = __shfl(idx, 1), b2 = __shfl(idx, 2), b3 = __shfl(idx, 3);
            int b4 = __shfl(idx, 4), b5 = __shfl(idx, 5), b6 = __shfl(idx, 6), b7 = __shfl(idx, 7);
            p0 = y[(size_t)(half ? b1 : b0) * 32 + fp];
            p1 = y[(size_t)(half ? b3 : b2) * 32 + fp];
            p2 = y[(size_t)(half ? b5 : b4) * 32 + fp];
            p3 = y[(size_t)(half ? b7 : b6) * 32 + fp];
            pend = true; j = 8;
        }
        for (; j + 8 <= cnt; j += 8) {
            int b0 = __shfl(idx, j),     b1 = __shfl(idx, j + 1), b2 = __shfl(idx, j + 2), b3 = __shfl(idx, j + 3);
            int b4 = __shfl(idx, j + 4), b5 = __shfl(idx, j + 5), b6 = __shfl(idx, j + 6), b7 = __shfl(idx, j + 7);
            uint_t q0 = y[(size_t)(half ? b1 : b0) * 32 + fp];
            uint_t q1 = y[(size_t)(half ? b3 : b2) * 32 + fp];
            uint_t q2 = y[(size_t)(half ? b5 : b4) * 32 + fp];
            uint_t q3 = y[(size_t)(half ? b7 : b6) * 32 + fp];
            a0 += unpk(p0); a1 += unpk(p1); a2 += unpk(p2); a3 += unpk(p3);
            p0 = q0; p1 = q1; p2 = q2; p3 = q3;
        }
        if (pend) {
            a0 += unpk(p0); a1 += unpk(p1); a2 += unpk(p2); a3 += unpk(p3);
        }
        for (; j + 2 <= cnt; j += 2) {
            int sA = __shfl(idx, j), sB = __shfl(idx, j + 1);
            a0 += unpk(y[(size_t)(half ? sB : sA) * 32 + fp]);
        }
        if (j < cnt) {
            int sA = __shfl(idx, j);
            if (half == 0) a0 += unpk(y[(size_t)sA * 32 + fp]);
        }
    }
    v2f at = (a0 + a1) + (a2 + a3);
    float ax = at.x, ay = at.y;
    ax += __shfl_xor(ax, 32);
    ay += __shfl_xor(ay, 32);
    axo = ax; ayo = ay;
}

// agg + relu epilogue (layers 1): writes f32 activations
__global__ void k_agg_bf(const int* __restrict__ rowptr, const int* __restrict__ rowend,
                         const int* __restrict__ csr, const uint_t* __restrict__ y,
                         const float* __restrict__ dinv, const float* __restrict__ bias,
                         float* __restrict__ out, int n) {
    int wave = (int)((blockIdx.x * (size_t)blockDim.x + threadIdx.x) >> 6);
    int lane = threadIdx.x & 63;
    if (wave >= n) return;
    int node = wave, half = lane >> 5, fp = lane & 31;
    float ax, ay;
    agg_core(rowptr, rowend, csr, y, node, lane, ax, ay);
    if (half == 0) {
        v2f sl = unpk(y[(size_t)node * 32 + fp]);     // self-loop
        ax += sl.x; ay += sl.y;
        float di = dinv[node];
        float2 b = *reinterpret_cast<const float2*>(bias + 2 * fp);
        float2 v;
        v.x = fmaxf(fmaf(di, ax, b.x), 0.f);
        v.y = fmaxf(fmaf(di, ay, b.y), 0.f);
        *reinterpret_cast<float2*>(out + (size_t)node * 64 + 2 * fp) = v;
    }
}

// agg + relu + fused head GEMM (h2 @ Wl + bl) -> final output [n,32]
__global__ __launch_bounds__(256) void k_agg_head(
        const int* __restrict__ rowptr, const int* __restrict__ rowend,
        const int* __restrict__ csr, const uint_t* __restrict__ y,
        const float* __restrict__ dinv, const float* __restrict__ b2,
        const float* __restrict__ Wl, const float* __restrict__ bl,
        float* __restrict__ out, int n) {
    __shared__ float WlS[64 * 32];
    for (int i = threadIdx.x; i < 64 * 32; i += 256) WlS[i] = Wl[i];
    __syncthreads();
    int wave = (int)((blockIdx.x * (size_t)blockDim.x + threadIdx.x) >> 6);
    int lane = threadIdx.x & 63;
    if (wave >= n) return;
    int node = wave, half = lane >> 5, fp = lane & 31;
    float ax, ay;
    agg_core(rowptr, rowend, csr, y, node, lane, ax, ay);
    // epilogue in BOTH halves (each lane ends with full h2[2fp], h2[2fp+1])
    v2f sl = unpk(y[(size_t)node * 32 + fp]);
    ax += sl.x; ay += sl.y;
    float di = dinv[node];
    float2 bb = *reinterpret_cast<const float2*>(b2 + 2 * fp);
    float h2x = fmaxf(fmaf(di, ax, bb.x), 0.f);
    float h2y = fmaxf(fmaf(di, ay, bb.y), 0.f);
    // head: out[c] = sum_k h2[k] * Wl[k][c] + bl[c]; halves split k-range
    float po = 0.f;
    #pragma unroll
    for (int k2 = 0; k2 < 16; k2++) {
        int k = (half << 4) + k2;          // pair index 0..31
        float hx = __shfl(h2x, k);
        float hy = __shfl(h2y, k);
        po = fmaf(hx, WlS[(2 * k) * 32 + fp], po);
        po = fmaf(hy, WlS[(2 * k + 1) * 32 + fp], po);
    }
    po += __shfl_xor(po, 32);
    if (half == 0) out[(size_t)node * 32 + fp] = po + bl[fp];
}

// ---------------- launch ----------------
extern "C" void kernel_launch(void* const* d_in, const int* in_sizes, int n_in,
                              void* d_out, int out_size, void* d_ws, size_t ws_size,
                              hipStream_t stream) {
    const float* x  = (const float*)d_in[0];
    const int*   ei = (const int*)d_in[1];
    const float* W1 = (const float*)d_in[2];
    const float* b1 = (const float*)d_in[3];
    const float* W2 = (const float*)d_in[4];
    const float* b2 = (const float*)d_in[5];
    const float* Wl = (const float*)d_in[6];
    const float* bl = (const float*)d_in[7];
    float* out = (float*)d_out;

    const int n = in_sizes[0] / 128;     // 100000
    const int E = in_sizes[1] / 2;       // 3200000
    const int* src = ei;
    const int* dst = ei + E;
    const int nbuk = (n + 255) >> 8;     // 391

    char* p = (char*)d_ws;
    auto alloc = [&](size_t bytes) { char* r = p; p += (bytes + 255) & ~(size_t)255; return r; };
    float* dinv   = (float*)alloc((size_t)n * 4);
    int*   bcur   = (int*)  alloc(MAXBUK * 4);
    int*   rowptr = (int*)  alloc((size_t)n * 4);
    int*   rowend = (int*)  alloc((size_t)n * 4);
    uint_t* ebuf  = (uint_t*)alloc((size_t)nbuk * CAP * 4 + 256);
    int*   csr    = (int*)  alloc((size_t)nbuk * CAP * 4 + 256);
    ushort_t* bufY = (ushort_t*)alloc((size_t)n * 64 * 2);  // bf16 msg table L1
    float* bufA   = (float*)alloc((size_t)n * 64 * 4);      // f32 activations
    ushort_t* bufB = (ushort_t*)alloc((size_t)n * 64 * 2);  // bf16 msg table L2
    (void)ws_size;

    k_init<<<1, 512, 0, stream>>>(bcur, nbuk);
    k_part2b<<<(E + PTILE - 1) / PTILE, 256, 0, stream>>>(src, dst, bcur, ebuf, E);
    k_csr<<<nbuk, 256, 0, stream>>>(ebuf, bcur, rowptr, rowend, dinv, csr, n);

    const int GB = (n + 63) / 64;
    const int AB = (n + 3) / 4;

    // layer 1
    k_gemm_t<128, 64, true, false, true><<<GB, 256, 0, stream>>>(x, W1, nullptr, dinv, bufY, n);
    k_agg_bf<<<AB, 256, 0, stream>>>(rowptr, rowend, csr, (const uint_t*)bufY, dinv, b1, bufA, n);

    // layer 2
    k_gemm_t<64, 64, true, false, true><<<GB, 256, 0, stream>>>(bufA, W2, nullptr, dinv, bufB, n);
    // layer-2 agg + head fused
    k_agg_head<<<AB, 256, 0, stream>>>(rowptr, rowend, csr, (const uint_t*)bufB, dinv, b2, Wl, bl, out, n);
}

// Round 9
// 311.573 us; speedup vs baseline: 2.3130x; 1.0427x over previous
//
#include <hip/hip_runtime.h>

#define MAXBUK 512          // fine buckets of 256 dst-nodes; n=100000 -> 391
#define PTILE 4096          // edges per k_part2 block
#define CAP   10240         // per-bucket capacity (mean 8192, +22 sigma)

typedef unsigned short ushort_t;
typedef unsigned int uint_t;
typedef float v2f __attribute__((ext_vector_type(2)));

__device__ inline v2f unpk(uint_t u) {
    v2f r;
    r.x = __uint_as_float(u << 16);
    r.y = __uint_as_float(u & 0xFFFF0000u);
    return r;
}
__device__ inline ushort_t f2bf(float f) {
    union { uint_t u; float f2; } c; c.f2 = f;
    uint_t r = c.u + 0x7FFFu + ((c.u >> 16) & 1u);   // round-to-nearest-even
    return (ushort_t)(r >> 16);
}

// ---------------- init per-bucket cursors ----------------
__global__ void k_init(int* __restrict__ bcur, int nbuk) {
    int t = threadIdx.x;
    if (t < nbuk) bcur[t] = t * CAP;
}

// ---------------- partition edges into capped bucket regions ----------------
// LDS-staged counting sort per 4096-edge tile; ebuf entry packed:
// (dst & 255) << 24 | src   (src < 2^24).
__global__ __launch_bounds__(256) void k_part2b(
        const int* __restrict__ src, const int* __restrict__ dst,
        int* __restrict__ bcur, uint_t* __restrict__ ebuf, int E) {
    __shared__ int hcnt[MAXBUK];
    __shared__ int lbase[MAXBUK];
    __shared__ int gbase[MAXBUK];
    __shared__ int hcur[MAXBUK];
    __shared__ int psum[256];
    __shared__ uint_t stage[PTILE];
    __shared__ unsigned short sbuk[PTILE];
    int t = threadIdx.x;
    int base = blockIdx.x * PTILE;
    int end = base + PTILE; if (end > E) end = E;
    int cnt = end - base;
    #pragma unroll
    for (int j = 0; j < MAXBUK / 256; j++) { hcnt[t + j * 256] = 0; hcur[t + j * 256] = 0; }
    __syncthreads();
    // P1: tile histogram
    for (int i = base + t; i < end; i += 256)
        atomicAdd(&hcnt[dst[i] >> 8], 1);
    __syncthreads();
    // P2: exclusive scan of hcnt (2/thread) + global reservation
    int a = hcnt[2 * t], b2 = hcnt[2 * t + 1];
    int ps = a + b2;
    psum[t] = ps;
    __syncthreads();
    for (int off = 1; off < 256; off <<= 1) {
        int u = (t >= off) ? psum[t - off] : 0;
        __syncthreads();
        psum[t] += u;
        __syncthreads();
    }
    int ex = psum[t] - ps;
    lbase[2 * t] = ex;
    lbase[2 * t + 1] = ex + a;
    __syncthreads();
    #pragma unroll
    for (int j = 0; j < MAXBUK / 256; j++) {
        int bk = t + j * 256;
        int c = hcnt[bk];
        gbase[bk] = c ? atomicAdd(&bcur[bk], c) : 0;
    }
    __syncthreads();
    // P3: stage bucket-major in LDS
    for (int i = base + t; i < end; i += 256) {
        int d = dst[i];
        int bk = d >> 8;
        int p = atomicAdd(&hcur[bk], 1);
        int sp = lbase[bk] + p;
        stage[sp] = ((uint_t)(d & 255) << 24) | (uint_t)src[i];
        sbuk[sp] = (unsigned short)bk;
    }
    __syncthreads();
    // P4: coalesced copy-out (contiguous run per bucket)
    for (int i = t; i < cnt; i += 256) {
        int bk = sbuk[i];
        ebuf[gbase[bk] + (i - lbase[bk])] = stage[i];
    }
}

// ---------------- per-bucket CSR assembly (one workgroup per bucket) --------
__global__ void k_csr(const uint_t* __restrict__ ebuf, const int* __restrict__ bend,
                      int* __restrict__ rowptr, int* __restrict__ rowend,
                      float* __restrict__ dinv, int* __restrict__ csr, int n) {
    __shared__ int hist[256];
    __shared__ int scan[256];
    __shared__ int cur[256];
    int b = blockIdx.x;
    int lo = b * CAP, hi = bend[b];
    int nodebase = b << 8;
    int t = threadIdx.x;
    hist[t] = 0;
    __syncthreads();
    for (int i = lo + t; i < hi; i += 256)
        atomicAdd(&hist[ebuf[i] >> 24], 1);
    __syncthreads();
    int deg = hist[t];
    scan[t] = deg;
    __syncthreads();
    for (int off = 1; off < 256; off <<= 1) {
        int u = (t >= off) ? scan[t - off] : 0;
        __syncthreads();
        scan[t] += u;
        __syncthreads();
    }
    int ex = scan[t] - deg;
    cur[t] = ex;
    int node = nodebase + t;
    if (node < n) {
        rowptr[node] = lo + ex;
        rowend[node] = lo + ex + deg;
        dinv[node] = rsqrtf((float)deg + 1.0f);
    }
    __syncthreads();
    for (int i = lo + t; i < hi; i += 256) {
        uint_t e = ebuf[i];
        int p = atomicAdd(&cur[e >> 24], 1);
        csr[lo + p] = (int)(e & 0xFFFFFFu);
    }
}

// ---------------- tiled GEMM (vector-ALU f32, register blocking) ------------
template<int K, int H, bool SCALE, bool BIAS, bool OBF16>
__global__ __launch_bounds__(256) void k_gemm_t(
        const float* __restrict__ X, const float* __restrict__ W,
        const float* __restrict__ bias, const float* __restrict__ dinv,
        void* __restrict__ Yv, int n) {
    constexpr int COLV = H / 16;
    __shared__ float Ws[K * H];
    __shared__ float XsT[64][65];
    int tid = threadIdx.x;
    for (int i = tid; i < K * H; i += 256) Ws[i] = W[i];
    int tr = tid >> 4;
    int tc = tid & 15;
    int rowBase = blockIdx.x * 64;
    float acc[4][COLV];
    #pragma unroll
    for (int i = 0; i < 4; i++)
        #pragma unroll
        for (int c = 0; c < COLV; c++) acc[i][c] = 0.f;

    for (int kc = 0; kc < K; kc += 64) {
        __syncthreads();
        #pragma unroll
        for (int j = 0; j < 4; j++) {
            int flat = tid + j * 256;
            int row = flat >> 4;
            int kv  = flat & 15;
            int gr = rowBase + row;
            float4 v = make_float4(0.f, 0.f, 0.f, 0.f);
            if (gr < n)
                v = *reinterpret_cast<const float4*>(X + (size_t)gr * K + kc + kv * 4);
            XsT[kv * 4 + 0][row] = v.x;
            XsT[kv * 4 + 1][row] = v.y;
            XsT[kv * 4 + 2][row] = v.z;
            XsT[kv * 4 + 3][row] = v.w;
        }
        __syncthreads();
        #pragma unroll
        for (int k = 0; k < 64; k++) {
            float a0 = XsT[k][tr * 4 + 0];
            float a1 = XsT[k][tr * 4 + 1];
            float a2 = XsT[k][tr * 4 + 2];
            float a3 = XsT[k][tr * 4 + 3];
            const float* bp = &Ws[(kc + k) * H + tc * COLV];
            #pragma unroll
            for (int c = 0; c < COLV; c++) {
                float b = bp[c];
                acc[0][c] = fmaf(a0, b, acc[0][c]);
                acc[1][c] = fmaf(a1, b, acc[1][c]);
                acc[2][c] = fmaf(a2, b, acc[2][c]);
                acc[3][c] = fmaf(a3, b, acc[3][c]);
            }
        }
    }
    #pragma unroll
    for (int i = 0; i < 4; i++) {
        int row = rowBase + tr * 4 + i;
        if (row >= n) continue;
        float s = SCALE ? dinv[row] : 1.f;
        float v[COLV];
        #pragma unroll
        for (int c = 0; c < COLV; c++) {
            float t2 = acc[i][c];
            if (SCALE) t2 *= s;
            if (BIAS)  t2 += bias[tc * COLV + c];
            v[c] = t2;
        }
        if (OBF16) {
            ushort_t* Y = (ushort_t*)Yv;
            ushort4 pk;
            pk.x = f2bf(v[0]); pk.y = f2bf(v[1]);
            pk.z = f2bf(v[2]); pk.w = f2bf(v[3]);
            *reinterpret_cast<ushort4*>(Y + (size_t)row * H + tc * COLV) = pk;
        } else {
            float* Y = (float*)Yv;
            float* yp = Y + (size_t)row * H + tc * COLV;
            if (COLV == 4)      *reinterpret_cast<float4*>(yp) = make_float4(v[0], v[1], v[2], v[3]);
            else                *reinterpret_cast<float2*>(yp) = make_float2(v[0], v[1]);
        }
    }
}

// ---------------- Aggregation: 4 edges per wave-gather -----------------------
// Quarter q = lane>>4 selects the edge; fp = lane&15 selects a uint2 (4 bf16
// features). ONE ds_bpermute (__shfl with per-lane index j+q) distributes 4
// edge indices; each lane does one 8B load per 4 edges. Quarter-reduce at end.
__global__ void k_agg_bf(const int* __restrict__ rowptr, const int* __restrict__ rowend,
                         const int* __restrict__ csr, const uint2* __restrict__ y2,
                         const float* __restrict__ dinv, const float* __restrict__ bias,
                         float* __restrict__ out, int n) {
    int wave = (int)((blockIdx.x * (size_t)blockDim.x + threadIdx.x) >> 6);
    int lane = threadIdx.x & 63;
    if (wave >= n) return;
    int node = wave;
    int q  = lane >> 4;      // 0..3: edge slot within group of 4
    int fp = lane & 15;      // uint2 index within row (features 4fp..4fp+3)
    v2f a0 = {0.f, 0.f}, a1 = {0.f, 0.f}, a2 = {0.f, 0.f}, a3 = {0.f, 0.f};
    int s = rowptr[node], e = rowend[node];
    for (int base = s; base < e; base += 64) {
        int rem = e - base; int cnt = rem > 64 ? 64 : rem;
        int idx = (base + lane < e) ? csr[base + lane] : 0;
        int j = 0;
        for (; j + 8 <= cnt; j += 8) {
            int s0 = __shfl(idx, j + q);
            int s1 = __shfl(idx, j + 4 + q);
            uint2 u0 = y2[(uint_t)s0 * 16 + fp];
            uint2 u1 = y2[(uint_t)s1 * 16 + fp];
            a0 += unpk(u0.x); a1 += unpk(u0.y);
            a2 += unpk(u1.x); a3 += unpk(u1.y);
        }
        for (; j + 4 <= cnt; j += 4) {
            int s0 = __shfl(idx, j + q);
            uint2 u0 = y2[(uint_t)s0 * 16 + fp];
            a0 += unpk(u0.x); a1 += unpk(u0.y);
        }
        if (j < cnt) {
            int r2 = cnt - j;                    // 1..3 tail edges
            int s0 = __shfl(idx, j + (q < r2 ? q : 0));
            if (q < r2) {
                uint2 u0 = y2[(uint_t)s0 * 16 + fp];
                a0 += unpk(u0.x); a1 += unpk(u0.y);
            }
        }
    }
    a0 += a2; a1 += a3;
    float f0 = a0.x, f1 = a0.y, f2 = a1.x, f3 = a1.y;
    f0 += __shfl_xor(f0, 16); f0 += __shfl_xor(f0, 32);
    f1 += __shfl_xor(f1, 16); f1 += __shfl_xor(f1, 32);
    f2 += __shfl_xor(f2, 16); f2 += __shfl_xor(f2, 32);
    f3 += __shfl_xor(f3, 16); f3 += __shfl_xor(f3, 32);
    if (q == 0) {
        uint2 su = y2[(uint_t)node * 16 + fp];   // self-loop
        v2f s0 = unpk(su.x), s1 = unpk(su.y);
        f0 += s0.x; f1 += s0.y; f2 += s1.x; f3 += s1.y;
        float di = dinv[node];
        float4 b = *reinterpret_cast<const float4*>(bias + 4 * fp);
        float4 v;
        v.x = fmaxf(fmaf(di, f0, b.x), 0.f);
        v.y = fmaxf(fmaf(di, f1, b.y), 0.f);
        v.z = fmaxf(fmaf(di, f2, b.z), 0.f);
        v.w = fmaxf(fmaf(di, f3, b.w), 0.f);
        *reinterpret_cast<float4*>(out + (size_t)node * 64 + 4 * fp) = v;
    }
}

// ---------------- launch ----------------
extern "C" void kernel_launch(void* const* d_in, const int* in_sizes, int n_in,
                              void* d_out, int out_size, void* d_ws, size_t ws_size,
                              hipStream_t stream) {
    const float* x  = (const float*)d_in[0];
    const int*   ei = (const int*)d_in[1];
    const float* W1 = (const float*)d_in[2];
    const float* b1 = (const float*)d_in[3];
    const float* W2 = (const float*)d_in[4];
    const float* b2 = (const float*)d_in[5];
    const float* Wl = (const float*)d_in[6];
    const float* bl = (const float*)d_in[7];
    float* out = (float*)d_out;

    const int n = in_sizes[0] / 128;     // 100000
    const int E = in_sizes[1] / 2;       // 3200000
    const int* src = ei;
    const int* dst = ei + E;
    const int nbuk = (n + 255) >> 8;     // 391

    char* p = (char*)d_ws;
    auto alloc = [&](size_t bytes) { char* r = p; p += (bytes + 255) & ~(size_t)255; return r; };
    float* dinv   = (float*)alloc((size_t)n * 4);
    int*   bcur   = (int*)  alloc(MAXBUK * 4);
    int*   rowptr = (int*)  alloc((size_t)n * 4);
    int*   rowend = (int*)  alloc((size_t)n * 4);
    uint_t* ebuf  = (uint_t*)alloc((size_t)nbuk * CAP * 4 + 256);
    int*   csr    = (int*)  alloc((size_t)nbuk * CAP * 4 + 256);
    ushort_t* bufY = (ushort_t*)alloc((size_t)n * 64 * 2);  // bf16 msg table L1
    float* bufA   = (float*)alloc((size_t)n * 64 * 4);      // f32 activations
    ushort_t* bufB = (ushort_t*)alloc((size_t)n * 64 * 2);  // bf16 msg table L2
    (void)ws_size;

    k_init<<<1, 512, 0, stream>>>(bcur, nbuk);
    k_part2b<<<(E + PTILE - 1) / PTILE, 256, 0, stream>>>(src, dst, bcur, ebuf, E);
    k_csr<<<nbuk, 256, 0, stream>>>(ebuf, bcur, rowptr, rowend, dinv, csr, n);

    const int GB = (n + 63) / 64;
    const int AB = (n + 3) / 4;

    // layer 1: y = dinv ⊙ (x @ W1) [bf16]; h1 = relu(dinv*agg + b1) [f32]
    k_gemm_t<128, 64, true, false, true><<<GB, 256, 0, stream>>>(x, W1, nullptr, dinv, bufY, n);
    k_agg_bf<<<AB, 256, 0, stream>>>(rowptr, rowend, csr, (const uint2*)bufY, dinv, b1, bufA, n);

    // layer 2
    k_gemm_t<64, 64, true, false, true><<<GB, 256, 0, stream>>>(bufA, W2, nullptr, dinv, bufB, n);
    k_agg_bf<<<AB, 256, 0, stream>>>(rowptr, rowend, csr, (const uint2*)bufB, dinv, b2, bufA, n);

    // head: out = h2 @ Wl + bl (f32, separate dense GEMM -- shfl-fused head
    // regressed: each __shfl is a full wave64 ds_bpermute, ~6.4M extra DS ops)
    k_gemm_t<64, 32, false, true, false><<<GB, 256, 0, stream>>>(bufA, Wl, bl, nullptr, out, n);
}